// Round 8
// baseline (745.850 us; speedup 1.0000x reference)
//
#include <hip/hip_runtime.h>
#include <hip/hip_bf16.h>
#include <hip/hip_fp16.h>

#define N_PTS 400000
#define XN 512
#define YN 512
#define BATCHN 4
#define VOX (XN*YN)            // 262144
#define GRID_NUM (BATCHN*VOX)  // 1048576

typedef unsigned long long u64;
typedef __attribute__((ext_vector_type(8))) _Float16 f16x8;
typedef __attribute__((ext_vector_type(4))) float f32x4;

static __device__ __forceinline__ float relu_(float x){ return fmaxf(x, 0.0f); }
static __device__ __forceinline__ int voxel_id(float px, float py, int b){
    int xg = (int)floorf(px*512.0f);
    int yg = (int)floorf(py*512.0f);
    return b*VOX + yg*XN + xg;
}

// ---- packed 4x fp16 helpers (values >= 0; fp16 bits of non-neg order as u16)
static __device__ __forceinline__ u64 packh4(const float* v){
    u64 r = 0;
    #pragma unroll
    for (int j=0;j<4;j++){
        unsigned short h = __half_as_ushort(__float2half_rn(v[j]));
        r |= (u64)h << (16*j);
    }
    return r;
}
static __device__ __forceinline__ void unpackh4(u64 w, float* o){
    #pragma unroll
    for (int j=0;j<4;j++)
        o[j] = __half2float(__ushort_as_half((unsigned short)(w >> (16*j))));
}
static __device__ __forceinline__ u64 pkmax4(u64 a, u64 b){
    u64 r = 0;
    #pragma unroll
    for (int j=0;j<4;j++){
        u64 x = (a >> (16*j)) & 0xFFFFull;
        u64 y = (b >> (16*j)) & 0xFFFFull;
        r |= (x > y ? x : y) << (16*j);
    }
    return r;
}

// ---------------- zero scratch each launch
__global__ void kZero(float4* __restrict__ p, int n4){
    int i = blockIdx.x*256 + threadIdx.x;
    const float4 z = make_float4(0.f,0.f,0.f,0.f);
    for (; i < n4; i += gridDim.x*256) p[i] = z;
}

// ---------------- diagnostic: ws too small -> encode ws MiB in output
__global__ void kDiag(float* __restrict__ o, int n, float v){
    int i = blockIdx.x*256 + threadIdx.x;
    for (; i < n; i += gridDim.x*256) o[i] = v;
}

// ---------------- histogram of voxel ids (+ cache gids)
__global__ void kHist(const int* __restrict__ bid, const float* __restrict__ pts,
                      unsigned* __restrict__ offs, int* __restrict__ gids)
{
    int i = blockIdx.x*256 + threadIdx.x;
    if (i >= N_PTS) return;
    int gid = voxel_id(pts[i], pts[N_PTS+i], bid[i]);
    gids[i] = gid;
    atomicAdd(&offs[gid], 1u);
}

// ---------------- 3-kernel exclusive scan of offs[GRID_NUM]
__global__ void kScan1(unsigned* __restrict__ offs, unsigned* __restrict__ partials)
{
    __shared__ unsigned sa[256], sb[256];
    const int t = threadIdx.x;
    const int g = blockIdx.x*256 + t;
    unsigned v = offs[g];
    sa[t] = v;
    __syncthreads();
    unsigned* src = sa; unsigned* dst = sb;
    #pragma unroll
    for (int d=1; d<256; d<<=1){
        dst[t] = src[t] + ((t>=d) ? src[t-d] : 0u);
        __syncthreads();
        unsigned* tmp = src; src = dst; dst = tmp;
    }
    unsigned incl = src[t];
    offs[g] = incl - v;                    // exclusive within block
    if (t == 255) partials[blockIdx.x] = incl;
}
__global__ void kScan2(unsigned* __restrict__ partials)   // 4096 entries, 1 block
{
    __shared__ unsigned sa[256], sb[256];
    const int t = threadIdx.x;
    unsigned loc[16]; unsigned sum = 0;
    #pragma unroll
    for (int j=0;j<16;j++){ loc[j] = partials[t*16+j]; sum += loc[j]; }
    sa[t] = sum;
    __syncthreads();
    unsigned* src = sa; unsigned* dst = sb;
    #pragma unroll
    for (int d=1; d<256; d<<=1){
        dst[t] = src[t] + ((t>=d) ? src[t-d] : 0u);
        __syncthreads();
        unsigned* tmp = src; src = dst; dst = tmp;
    }
    unsigned run = src[t] - sum;           // exclusive base for this thread
    #pragma unroll
    for (int j=0;j<16;j++){ unsigned c = loc[j]; partials[t*16+j] = run; run += c; }
}
__global__ void kScan3(unsigned* __restrict__ offs, const unsigned* __restrict__ partials)
{
    int g = blockIdx.x*256 + threadIdx.x;
    offs[g] += partials[blockIdx.x];
}

// ---------------- Kernel A: MLPs -> obufA (packed fp16), place index in order[]
__global__ void kA(const int* __restrict__ bid, const float* __restrict__ pts,
                   const int* __restrict__ gids,
                   const float* __restrict__ w0, const float* __restrict__ b0,
                   const float* __restrict__ s0, const float* __restrict__ t0,
                   const float* __restrict__ w1, const float* __restrict__ b1,
                   const float* __restrict__ s1, const float* __restrict__ t1,
                   const float* __restrict__ wv0, const float* __restrict__ bv0,
                   const float* __restrict__ sv0, const float* __restrict__ tv0,
                   u64* __restrict__ obufA,
                   unsigned* __restrict__ offs, unsigned* __restrict__ order)
{
    int i = blockIdx.x*256 + threadIdx.x;
    if (i >= N_PTS) return;
    float p[6];
    #pragma unroll
    for (int r=0;r<6;r++) p[r] = pts[r*N_PTS+i];
    int xg = (int)floorf(p[0]*512.0f);
    int yg = (int)floorf(p[1]*512.0f);

    float h0[16];
    #pragma unroll
    for (int o=0;o<16;o++){
        float a = b0[o];
        #pragma unroll
        for (int k=0;k<6;k++) a = fmaf(w0[o*6+k], p[k], a);
        h0[o] = relu_(fmaf(a, s0[o], t0[o]));
    }
    float h1[16];
    #pragma unroll
    for (int o=0;o<16;o++){
        float a = b1[o];
        #pragma unroll
        for (int k=0;k<16;k++) a = fmaf(w1[o*16+k], h0[k], a);
        h1[o] = relu_(fmaf(a, s1[o], t1[o]));
    }
    float dx = p[0] - ((float)xg + 0.5f)*(1.0f/512.0f);
    float dy = p[1] - ((float)yg + 0.5f)*(1.0f/512.0f);
    float vv[16];
    #pragma unroll
    for (int o=0;o<16;o++){
        float a = bv0[o];
        #pragma unroll
        for (int k=0;k<16;k++) a = fmaf(wv0[o*18+k], h1[k], a);
        a = fmaf(wv0[o*18+16], dx, a);
        a = fmaf(wv0[o*18+17], dy, a);
        vv[o] = relu_(fmaf(a, sv0[o], tv0[o]));
    }
    u64* op = obufA + (size_t)i*4;
    #pragma unroll
    for (int q=0;q<4;q++) op[q] = packh4(&vv[q*4]);

    int gid = gids[i];
    unsigned pos = atomicAdd(&offs[gid], 1u);
    order[pos] = (unsigned)i;
}

// ---------------- per-voxel max over its points: 16ch (4 u64 words)
__global__ void kSegMax(const unsigned* __restrict__ offs, const unsigned* __restrict__ order,
                        const u64* __restrict__ src, u64* __restrict__ dst)
{
    int v = blockIdx.x*256 + threadIdx.x;
    unsigned s = v ? offs[v-1] : 0u;
    unsigned e = offs[v];
    if (e <= s) return;
    u64 m0=0,m1=0,m2=0,m3=0;
    for (unsigned p=s; p<e; ++p){
        const u64* q = src + (size_t)order[p]*4;
        m0 = pkmax4(m0, q[0]); m1 = pkmax4(m1, q[1]);
        m2 = pkmax4(m2, q[2]); m3 = pkmax4(m3, q[3]);
    }
    u64* d = dst + (size_t)v*4;
    d[0]=m0; d[1]=m1; d[2]=m2; d[3]=m3;
}

// ---------------- per-voxel max, 32ch (8 u64), write ALL voxels (zeros if empty) = NHWC fp16 grid
__global__ void kGridMax(const unsigned* __restrict__ offs, const unsigned* __restrict__ order,
                         const u64* __restrict__ src, u64* __restrict__ dst)
{
    int v = blockIdx.x*256 + threadIdx.x;
    unsigned s = v ? offs[v-1] : 0u;
    unsigned e = offs[v];
    u64 m[8];
    #pragma unroll
    for (int q=0;q<8;q++) m[q] = 0ull;
    for (unsigned p=s; p<e; ++p){
        const u64* q = src + (size_t)order[p]*8;
        #pragma unroll
        for (int j=0;j<8;j++) m[j] = pkmax4(m[j], q[j]);
    }
    u64* d = dst + (size_t)v*8;
    #pragma unroll
    for (int q=0;q<8;q++) d[q] = m[q];
}

// ---------------- Kernel B: concat(obufA, seg0[gid]) -> pconv(v1) -> obufB
__global__ void kB(const int* __restrict__ gids,
                   const float* __restrict__ w, const float* __restrict__ bb,
                   const float* __restrict__ ss, const float* __restrict__ tt,
                   const u64* __restrict__ obufA, const u64* __restrict__ seg0,
                   u64* __restrict__ obufB)
{
    int i = blockIdx.x*256 + threadIdx.x;
    if (i >= N_PTS) return;
    int gid = gids[i];
    float h[32];
    const u64* ap = obufA + (size_t)i*4;
    #pragma unroll
    for (int q=0;q<4;q++) unpackh4(ap[q], &h[q*4]);
    const u64* sp = seg0 + (size_t)gid*4;
    #pragma unroll
    for (int q=0;q<4;q++) unpackh4(sp[q], &h[16+q*4]);

    float o[16];
    #pragma unroll
    for (int c=0;c<16;c++){
        float a = bb[c];
        #pragma unroll
        for (int k=0;k<32;k++) a = fmaf(w[c*32+k], h[k], a);
        o[c] = relu_(fmaf(a, ss[c], tt[c]));
    }
    u64* op = obufB + (size_t)i*4;
    #pragma unroll
    for (int q=0;q<4;q++) op[q] = packh4(&o[q*4]);
}

// ---------------- Kernel C: concat(obufB, seg1[gid]) -> pconv(w2)=point0 -> pbuf,
//                  pre-project through w3[:, :32] into d_out
__global__ void kC(const int* __restrict__ gids,
                   const float* __restrict__ w, const float* __restrict__ bb,
                   const float* __restrict__ ss, const float* __restrict__ tt,
                   const float* __restrict__ w3,
                   const u64* __restrict__ obufB, const u64* __restrict__ seg1,
                   u64* __restrict__ pbuf, float* __restrict__ outp)
{
    int i = blockIdx.x*256 + threadIdx.x;
    if (i >= N_PTS) return;
    int gid = gids[i];
    float h[32];
    const u64* ap = obufB + (size_t)i*4;
    #pragma unroll
    for (int q=0;q<4;q++) unpackh4(ap[q], &h[q*4]);
    const u64* sp = seg1 + (size_t)gid*4;
    #pragma unroll
    for (int q=0;q<4;q++) unpackh4(sp[q], &h[16+q*4]);

    float p0v[32];
    #pragma unroll
    for (int c=0;c<32;c++){
        float a = bb[c];
        #pragma unroll
        for (int k=0;k<32;k++) a = fmaf(w[c*32+k], h[k], a);
        p0v[c] = relu_(fmaf(a, ss[c], tt[c]));
    }
    u64* pp = pbuf + (size_t)i*8;
    #pragma unroll
    for (int q=0;q<8;q++) pp[q] = packh4(&p0v[q*4]);
    #pragma unroll
    for (int k=0;k<20;k++){
        float a = 0.f;
        #pragma unroll
        for (int c=0;c<32;c++) a = fmaf(w3[k*64+c], p0v[c], a);
        outp[(size_t)k*N_PTS+i] = a;
    }
}

// ---------------- dilated 3x3 conv + BN + ReLU via MFMA implicit GEMM
// in/out: NHWC fp16 [4][512][512][32]; A-fragments read DIRECTLY from global
// (coalesced 1KB/wave; tap-overlap served by L1/L2). Weights staged in 18KB LDS.
template<int P, bool EDGE>
static __device__ __forceinline__ void conv_core(
    const _Float16* __restrict__ inB, const f16x8* __restrict__ pW,
    int y0, int x0, int rowbase, int lane, f32x4 acc[8][2])
{
    const int lx = lane & 15, chunk = (lane >> 4) * 8;
    #pragma unroll
    for (int t=0;t<9;t++){
        const int ky = t/3, kx = t%3;
        f16x8 b0 = pW[(t*2+0)*64 + lane];
        f16x8 b1 = pW[(t*2+1)*64 + lane];
        #pragma unroll
        for (int m=0;m<8;m++){
            int gy = y0 + rowbase + (m>>1) + ky*P - P;
            int gx = x0 + (m&1)*16 + kx*P - P + lx;
            f16x8 a;
            if (EDGE){
                bool v = ((unsigned)gy < 512u) && ((unsigned)gx < 512u);
                int cy = v ? gy : 0, cx = v ? gx : 0;
                a = *(const f16x8*)(inB + ((size_t)cy*512 + cx)*32 + chunk);
                if (!v) a = (f16x8)(_Float16)0.0f;
            } else {
                a = *(const f16x8*)(inB + ((size_t)gy*512 + gx)*32 + chunk);
            }
            acc[m][0] = __builtin_amdgcn_mfma_f32_16x16x32_f16(a, b0, acc[m][0], 0,0,0);
            acc[m][1] = __builtin_amdgcn_mfma_f32_16x16x32_f16(a, b1, acc[m][1], 0,0,0);
        }
    }
}

template<int P>
__global__ __launch_bounds__(256,4) void convM(
    const _Float16* __restrict__ in, _Float16* __restrict__ out,
    const float* __restrict__ W32, const float* __restrict__ bb,
    const float* __restrict__ ss, const float* __restrict__ tt)
{
    constexpr int TW = 32, TH = 16;
    __shared__ uint4 sW4[9*2*64];          // 18 KB weight fragments
    const int tid = threadIdx.x;
    const int lane = tid & 63, wv = tid >> 6;
    const int x0 = blockIdx.x*TW, y0 = blockIdx.y*TH, bz = blockIdx.z;
    const _Float16* inB = in + (size_t)bz*VOX*32;

    {
        _Float16* sWh = (_Float16*)sW4;
        for (int idx = tid; idx < 9216; idx += 256){
            int j = idx & 7, ln = (idx>>3) & 63, rest = idx >> 9;
            int t = rest >> 1, nt = rest & 1;
            int ic = (ln>>4)*8 + j, oc = nt*16 + (ln&15);
            sWh[idx] = (_Float16)W32[((size_t)oc*32 + ic)*9 + t];
        }
    }
    __syncthreads();

    const f16x8* pW = (const f16x8*)sW4;
    const int rowbase = wv*4;

    f32x4 acc[8][2];
    #pragma unroll
    for (int m=0;m<8;m++){ acc[m][0]=(f32x4)0.f; acc[m][1]=(f32x4)0.f; }

    const bool interior = (x0 >= P) && (x0 + TW + P <= XN) && (y0 >= P) && (y0 + TH + P <= YN);
    if (interior) conv_core<P,false>(inB, pW, y0, x0, rowbase, lane, acc);
    else          conv_core<P,true >(inB, pW, y0, x0, rowbase, lane, acc);

    float bn[2], sn[2], tn[2];
    #pragma unroll
    for (int n=0;n<2;n++){
        int oc = n*16 + (lane&15);
        bn[n] = bb[oc]; sn[n] = ss[oc]; tn[n] = tt[oc];
    }
    _Float16* outB = out + (size_t)bz*VOX*32;
    #pragma unroll
    for (int m=0;m<8;m++){
        int y = y0 + rowbase + (m>>1);
        int xb = x0 + (m&1)*16 + (lane>>4)*4;
        #pragma unroll
        for (int n=0;n<2;n++){
            int oc = n*16 + (lane&15);
            #pragma unroll
            for (int r=0;r<4;r++){
                float v = relu_(fmaf(acc[m][n][r] + bn[n], sn[n], tn[n]));
                outB[(((size_t)y*512) + (xb + r))*32 + oc] = (_Float16)v;
            }
        }
    }
}

// ---------------- bilinear sample (NHWC fp16 grid) + add w3[:,32:]@point1 + b3
__global__ void kFinal(const int* __restrict__ bid, const float* __restrict__ pts,
                       const _Float16* __restrict__ gridH,
                       const float* __restrict__ w3, const float* __restrict__ b3,
                       float* __restrict__ outp)
{
    int i = blockIdx.x*256 + threadIdx.x;
    if (i >= N_PTS) return;
    float px = pts[i], py = pts[N_PTS+i];
    int b = bid[i];
    float ix = px*512.0f - 1.0f;
    float iy = py*512.0f - 1.0f + (float)(b*512);
    float x0f = floorf(ix), y0f = floorf(iy);
    float wx = ix - x0f, wy = iy - y0f;
    int x0 = (int)x0f, y0 = (int)y0f;

    float p1[32];
    #pragma unroll
    for (int c=0;c<32;c++) p1[c] = 0.f;
    #pragma unroll
    for (int t=0;t<4;t++){
        int yi = y0 + (t>>1);
        int xi = x0 + (t&1);
        if (yi < 0 || yi >= BATCHN*YN || xi < 0 || xi >= XN) continue;
        float wgt = ((t>>1)? wy : 1.0f-wy) * ((t&1)? wx : 1.0f-wx);
        const uint4* tp = (const uint4*)(gridH + ((size_t)yi*XN + xi)*32);
        #pragma unroll
        for (int q=0;q<4;q++){
            uint4 v = tp[q];
            const unsigned int* vu = (const unsigned int*)&v;
            #pragma unroll
            for (int e=0;e<4;e++){
                float lo = __half2float(__ushort_as_half((unsigned short)(vu[e] & 0xFFFF)));
                float hi = __half2float(__ushort_as_half((unsigned short)(vu[e] >> 16)));
                p1[q*8 + e*2 + 0] = fmaf(wgt, lo, p1[q*8 + e*2 + 0]);
                p1[q*8 + e*2 + 1] = fmaf(wgt, hi, p1[q*8 + e*2 + 1]);
            }
        }
    }

    #pragma unroll
    for (int k=0;k<20;k++){
        float a = outp[(size_t)k*N_PTS + i] + b3[k];
        #pragma unroll
        for (int c=0;c<32;c++) a = fmaf(w3[k*64+32+c], p1[c], a);
        outp[(size_t)k*N_PTS + i] = a;
    }
}

extern "C" void kernel_launch(void* const* d_in, const int* in_sizes, int n_in,
                              void* d_out, int out_size, void* d_ws, size_t ws_size,
                              hipStream_t stream)
{
    const int*   bid = (const int*)  d_in[0];
    const float* pts = (const float*)d_in[1];
    const float* w0  = (const float*)d_in[3];
    const float* b0  = (const float*)d_in[4];
    const float* s0  = (const float*)d_in[5];
    const float* t0  = (const float*)d_in[6];
    const float* w1  = (const float*)d_in[7];
    const float* b1  = (const float*)d_in[8];
    const float* s1  = (const float*)d_in[9];
    const float* t1  = (const float*)d_in[10];
    const float* wv0 = (const float*)d_in[11];
    const float* bv0 = (const float*)d_in[12];
    const float* sv0 = (const float*)d_in[13];
    const float* tv0 = (const float*)d_in[14];
    const float* wv1 = (const float*)d_in[15];
    const float* bv1 = (const float*)d_in[16];
    const float* sv1 = (const float*)d_in[17];
    const float* tv1 = (const float*)d_in[18];
    const float* w2  = (const float*)d_in[19];
    const float* b2  = (const float*)d_in[20];
    const float* s2  = (const float*)d_in[21];
    const float* t2  = (const float*)d_in[22];
    const float* w2d = (const float*)d_in[23];
    const float* b2d = (const float*)d_in[24];
    const float* s2d = (const float*)d_in[25];
    const float* t2d = (const float*)d_in[26];
    const float* w3  = (const float*)d_in[27];
    const float* b3  = (const float*)d_in[28];

    const size_t MB = 1024*1024;
    const size_t NEED = 192*MB;
    if (ws_size < NEED){
        kDiag<<<512,256,0,stream>>>((float*)d_out, out_size, (float)(ws_size>>20));
        return;
    }

    char* ws = (char*)d_ws;
    u64*      gridV    = (u64*)ws;                        // 64 MiB NHWC fp16 (conv ping)
    _Float16* ping     = (_Float16*)ws;
    _Float16* pong     = (_Float16*)(ws + 64*MB);         // 64 MiB (conv pong)
    u64*      seg0     = (u64*)(ws + 64*MB);              // 32 MiB, alias pong (dead before conv0)
    u64*      seg1     = (u64*)(ws + 96*MB);              // 32 MiB, alias pong
    unsigned* offs     = (unsigned*)(ws + 128*MB);        // 4 MiB hist/offsets
    unsigned* partials = (unsigned*)(ws + 132*MB);        // 16 KiB
    unsigned* order    = (unsigned*)(ws + 133*MB);        // 1.6 MiB
    int*      gids     = (int*)(ws + 135*MB);             // 1.6 MiB
    u64*      obufA    = (u64*)(ws + 137*MB);             // 12.8 MiB [pt][16ch fp16]
    u64*      obufB    = (u64*)(ws + 150*MB);             // 12.8 MiB
    u64*      pbuf     = (u64*)(ws + 163*MB);             // 25.6 MiB [pt][32ch fp16]

    // zero the histogram only
    kZero<<<256,256,0,stream>>>((float4*)offs, (int)(GRID_NUM*4/16));

    const int nb = (N_PTS + 255)/256;
    const int nv = GRID_NUM/256;                          // 4096

    kHist <<<nb,256,0,stream>>>(bid, pts, offs, gids);
    kScan1<<<nv,256,0,stream>>>(offs, partials);
    kScan2<<<1,256,0,stream>>>(partials);
    kScan3<<<nv,256,0,stream>>>(offs, partials);

    kA<<<nb,256,0,stream>>>(bid, pts, gids, w0,b0,s0,t0, w1,b1,s1,t1,
                            wv0,bv0,sv0,tv0, obufA, offs, order);
    kSegMax<<<nv,256,0,stream>>>(offs, order, obufA, seg0);
    kB<<<nb,256,0,stream>>>(gids, wv1,bv1,sv1,tv1, obufA, seg0, obufB);
    kSegMax<<<nv,256,0,stream>>>(offs, order, obufB, seg1);
    kC<<<nb,256,0,stream>>>(gids, w2,b2,s2,t2, w3, obufB, seg1, pbuf, (float*)d_out);
    kGridMax<<<nv,256,0,stream>>>(offs, order, pbuf, gridV);

    dim3 cgrid(XN/32, YN/16, BATCHN);
    convM<1><<<cgrid,256,0,stream>>>(ping, pong, w2d + 0*9216, b2d + 0,  s2d + 0,  t2d + 0);
    convM<2><<<cgrid,256,0,stream>>>(pong, ping, w2d + 1*9216, b2d + 32, s2d + 32, t2d + 32);
    convM<2><<<cgrid,256,0,stream>>>(ping, pong, w2d + 2*9216, b2d + 64, s2d + 64, t2d + 64);
    convM<2><<<cgrid,256,0,stream>>>(pong, ping, w2d + 3*9216, b2d + 96, s2d + 96, t2d + 96);

    kFinal<<<nb,256,0,stream>>>(bid, pts, ping, w3, b3, (float*)d_out);
}

// Round 9
// 482.813 us; speedup vs baseline: 1.5448x; 1.5448x over previous
//
#include <hip/hip_runtime.h>
#include <hip/hip_bf16.h>
#include <hip/hip_fp16.h>

#define N_PTS 400000
#define XN 512
#define YN 512
#define BATCHN 4
#define VOX (XN*YN)            // 262144
#define GRID_NUM (BATCHN*VOX)  // 1048576

typedef unsigned long long u64;
typedef __attribute__((ext_vector_type(8))) _Float16 f16x8;
typedef __attribute__((ext_vector_type(4))) float f32x4;

static __device__ __forceinline__ float relu_(float x){ return fmaxf(x, 0.0f); }
static __device__ __forceinline__ int voxel_id(float px, float py, int b){
    int xg = (int)floorf(px*512.0f);
    int yg = (int)floorf(py*512.0f);
    return b*VOX + yg*XN + xg;
}

// ---- packed 4x fp16 helpers (values >= 0; fp16 bits of non-neg order as u16)
static __device__ __forceinline__ u64 packh4(const float* v){
    u64 r = 0;
    #pragma unroll
    for (int j=0;j<4;j++){
        unsigned short h = __half_as_ushort(__float2half_rn(v[j]));
        r |= (u64)h << (16*j);
    }
    return r;
}
static __device__ __forceinline__ void unpackh4(u64 w, float* o){
    #pragma unroll
    for (int j=0;j<4;j++)
        o[j] = __half2float(__ushort_as_half((unsigned short)(w >> (16*j))));
}
static __device__ __forceinline__ u64 pkmax4(u64 a, u64 b){
    u64 r = 0;
    #pragma unroll
    for (int j=0;j<4;j++){
        u64 x = (a >> (16*j)) & 0xFFFFull;
        u64 y = (b >> (16*j)) & 0xFFFFull;
        r |= (x > y ? x : y) << (16*j);
    }
    return r;
}

// ---------------- zero scratch each launch
__global__ void kZero(float4* __restrict__ p, int n4){
    int i = blockIdx.x*256 + threadIdx.x;
    const float4 z = make_float4(0.f,0.f,0.f,0.f);
    for (; i < n4; i += gridDim.x*256) p[i] = z;
}

// ---------------- diagnostic: ws too small -> encode ws MiB in output
__global__ void kDiag(float* __restrict__ o, int n, float v){
    int i = blockIdx.x*256 + threadIdx.x;
    for (; i < n; i += gridDim.x*256) o[i] = v;
}

// ---------------- histogram of voxel ids (+ cache gids)
__global__ void kHist(const int* __restrict__ bid, const float* __restrict__ pts,
                      unsigned* __restrict__ offs, int* __restrict__ gids)
{
    int i = blockIdx.x*256 + threadIdx.x;
    if (i >= N_PTS) return;
    int gid = voxel_id(pts[i], pts[N_PTS+i], bid[i]);
    gids[i] = gid;
    atomicAdd(&offs[gid], 1u);
}

// ---------------- 3-kernel exclusive scan of offs[GRID_NUM]
__global__ void kScan1(unsigned* __restrict__ offs, unsigned* __restrict__ partials)
{
    __shared__ unsigned sa[256], sb[256];
    const int t = threadIdx.x;
    const int g = blockIdx.x*256 + t;
    unsigned v = offs[g];
    sa[t] = v;
    __syncthreads();
    unsigned* src = sa; unsigned* dst = sb;
    #pragma unroll
    for (int d=1; d<256; d<<=1){
        dst[t] = src[t] + ((t>=d) ? src[t-d] : 0u);
        __syncthreads();
        unsigned* tmp = src; src = dst; dst = tmp;
    }
    unsigned incl = src[t];
    offs[g] = incl - v;                    // exclusive within block
    if (t == 255) partials[blockIdx.x] = incl;
}
__global__ void kScan2(unsigned* __restrict__ partials)   // 4096 entries, 1 block
{
    __shared__ unsigned sa[256], sb[256];
    const int t = threadIdx.x;
    unsigned loc[16]; unsigned sum = 0;
    #pragma unroll
    for (int j=0;j<16;j++){ loc[j] = partials[t*16+j]; sum += loc[j]; }
    sa[t] = sum;
    __syncthreads();
    unsigned* src = sa; unsigned* dst = sb;
    #pragma unroll
    for (int d=1; d<256; d<<=1){
        dst[t] = src[t] + ((t>=d) ? src[t-d] : 0u);
        __syncthreads();
        unsigned* tmp = src; src = dst; dst = tmp;
    }
    unsigned run = src[t] - sum;           // exclusive base for this thread
    #pragma unroll
    for (int j=0;j<16;j++){ unsigned c = loc[j]; partials[t*16+j] = run; run += c; }
}
__global__ void kScan3(unsigned* __restrict__ offs, const unsigned* __restrict__ partials)
{
    int g = blockIdx.x*256 + threadIdx.x;
    offs[g] += partials[blockIdx.x];
}

// ---------------- Kernel A: MLPs -> obufA (packed fp16), place index in order[]
__global__ void kA(const int* __restrict__ bid, const float* __restrict__ pts,
                   const int* __restrict__ gids,
                   const float* __restrict__ w0, const float* __restrict__ b0,
                   const float* __restrict__ s0, const float* __restrict__ t0,
                   const float* __restrict__ w1, const float* __restrict__ b1,
                   const float* __restrict__ s1, const float* __restrict__ t1,
                   const float* __restrict__ wv0, const float* __restrict__ bv0,
                   const float* __restrict__ sv0, const float* __restrict__ tv0,
                   u64* __restrict__ obufA,
                   unsigned* __restrict__ offs, unsigned* __restrict__ order)
{
    int i = blockIdx.x*256 + threadIdx.x;
    if (i >= N_PTS) return;
    float p[6];
    #pragma unroll
    for (int r=0;r<6;r++) p[r] = pts[r*N_PTS+i];
    int xg = (int)floorf(p[0]*512.0f);
    int yg = (int)floorf(p[1]*512.0f);

    float h0[16];
    #pragma unroll
    for (int o=0;o<16;o++){
        float a = b0[o];
        #pragma unroll
        for (int k=0;k<6;k++) a = fmaf(w0[o*6+k], p[k], a);
        h0[o] = relu_(fmaf(a, s0[o], t0[o]));
    }
    float h1[16];
    #pragma unroll
    for (int o=0;o<16;o++){
        float a = b1[o];
        #pragma unroll
        for (int k=0;k<16;k++) a = fmaf(w1[o*16+k], h0[k], a);
        h1[o] = relu_(fmaf(a, s1[o], t1[o]));
    }
    float dx = p[0] - ((float)xg + 0.5f)*(1.0f/512.0f);
    float dy = p[1] - ((float)yg + 0.5f)*(1.0f/512.0f);
    float vv[16];
    #pragma unroll
    for (int o=0;o<16;o++){
        float a = bv0[o];
        #pragma unroll
        for (int k=0;k<16;k++) a = fmaf(wv0[o*18+k], h1[k], a);
        a = fmaf(wv0[o*18+16], dx, a);
        a = fmaf(wv0[o*18+17], dy, a);
        vv[o] = relu_(fmaf(a, sv0[o], tv0[o]));
    }
    u64* op = obufA + (size_t)i*4;
    #pragma unroll
    for (int q=0;q<4;q++) op[q] = packh4(&vv[q*4]);

    int gid = gids[i];
    unsigned pos = atomicAdd(&offs[gid], 1u);
    order[pos] = (unsigned)i;
}

// ---------------- per-voxel max over its points: 16ch (4 u64 words)
__global__ void kSegMax(const unsigned* __restrict__ offs, const unsigned* __restrict__ order,
                        const u64* __restrict__ src, u64* __restrict__ dst)
{
    int v = blockIdx.x*256 + threadIdx.x;
    unsigned s = v ? offs[v-1] : 0u;
    unsigned e = offs[v];
    if (e <= s) return;
    u64 m0=0,m1=0,m2=0,m3=0;
    for (unsigned p=s; p<e; ++p){
        const u64* q = src + (size_t)order[p]*4;
        m0 = pkmax4(m0, q[0]); m1 = pkmax4(m1, q[1]);
        m2 = pkmax4(m2, q[2]); m3 = pkmax4(m3, q[3]);
    }
    u64* d = dst + (size_t)v*4;
    d[0]=m0; d[1]=m1; d[2]=m2; d[3]=m3;
}

// ---------------- per-voxel max, 32ch (8 u64), write ALL voxels (zeros if empty) = NHWC fp16 grid
__global__ void kGridMax(const unsigned* __restrict__ offs, const unsigned* __restrict__ order,
                         const u64* __restrict__ src, u64* __restrict__ dst)
{
    int v = blockIdx.x*256 + threadIdx.x;
    unsigned s = v ? offs[v-1] : 0u;
    unsigned e = offs[v];
    u64 m[8];
    #pragma unroll
    for (int q=0;q<8;q++) m[q] = 0ull;
    for (unsigned p=s; p<e; ++p){
        const u64* q = src + (size_t)order[p]*8;
        #pragma unroll
        for (int j=0;j<8;j++) m[j] = pkmax4(m[j], q[j]);
    }
    u64* d = dst + (size_t)v*8;
    #pragma unroll
    for (int q=0;q<8;q++) d[q] = m[q];
}

// ---------------- Kernel B: concat(obufA, seg0[gid]) -> pconv(v1) -> obufB
__global__ void kB(const int* __restrict__ gids,
                   const float* __restrict__ w, const float* __restrict__ bb,
                   const float* __restrict__ ss, const float* __restrict__ tt,
                   const u64* __restrict__ obufA, const u64* __restrict__ seg0,
                   u64* __restrict__ obufB)
{
    int i = blockIdx.x*256 + threadIdx.x;
    if (i >= N_PTS) return;
    int gid = gids[i];
    float h[32];
    const u64* ap = obufA + (size_t)i*4;
    #pragma unroll
    for (int q=0;q<4;q++) unpackh4(ap[q], &h[q*4]);
    const u64* sp = seg0 + (size_t)gid*4;
    #pragma unroll
    for (int q=0;q<4;q++) unpackh4(sp[q], &h[16+q*4]);

    float o[16];
    #pragma unroll
    for (int c=0;c<16;c++){
        float a = bb[c];
        #pragma unroll
        for (int k=0;k<32;k++) a = fmaf(w[c*32+k], h[k], a);
        o[c] = relu_(fmaf(a, ss[c], tt[c]));
    }
    u64* op = obufB + (size_t)i*4;
    #pragma unroll
    for (int q=0;q<4;q++) op[q] = packh4(&o[q*4]);
}

// ---------------- Kernel C: concat(obufB, seg1[gid]) -> pconv(w2)=point0 -> pbuf,
//                  pre-project through w3[:, :32] into d_out
__global__ void kC(const int* __restrict__ gids,
                   const float* __restrict__ w, const float* __restrict__ bb,
                   const float* __restrict__ ss, const float* __restrict__ tt,
                   const float* __restrict__ w3,
                   const u64* __restrict__ obufB, const u64* __restrict__ seg1,
                   u64* __restrict__ pbuf, float* __restrict__ outp)
{
    int i = blockIdx.x*256 + threadIdx.x;
    if (i >= N_PTS) return;
    int gid = gids[i];
    float h[32];
    const u64* ap = obufB + (size_t)i*4;
    #pragma unroll
    for (int q=0;q<4;q++) unpackh4(ap[q], &h[q*4]);
    const u64* sp = seg1 + (size_t)gid*4;
    #pragma unroll
    for (int q=0;q<4;q++) unpackh4(sp[q], &h[16+q*4]);

    float p0v[32];
    #pragma unroll
    for (int c=0;c<32;c++){
        float a = bb[c];
        #pragma unroll
        for (int k=0;k<32;k++) a = fmaf(w[c*32+k], h[k], a);
        p0v[c] = relu_(fmaf(a, ss[c], tt[c]));
    }
    u64* pp = pbuf + (size_t)i*8;
    #pragma unroll
    for (int q=0;q<8;q++) pp[q] = packh4(&p0v[q*4]);
    #pragma unroll
    for (int k=0;k<20;k++){
        float a = 0.f;
        #pragma unroll
        for (int c=0;c<32;c++) a = fmaf(w3[k*64+c], p0v[c], a);
        outp[(size_t)k*N_PTS+i] = a;
    }
}

// ---------------- dilated 3x3 conv + BN + ReLU via MFMA implicit GEMM
// NHWC fp16. LDS-staged A (stride-5-uint4 pad, 0 conflicts) + weight frags.
// SWAPPED operands: mfma(W_frag, A_frag) -> D[oc][px]; lane holds 4 consecutive
// oc at one px -> 8B packed stores, fully coalesced 64B lines per px.
template<int P>
__global__ __launch_bounds__(256,3) void convM(
    const _Float16* __restrict__ in, _Float16* __restrict__ out,
    const float* __restrict__ W32, const float* __restrict__ bb,
    const float* __restrict__ ss, const float* __restrict__ tt)
{
    constexpr int TW = 32, TH = 8;
    constexpr int TIW = TW + 2*P, TIH = TH + 2*P;   // P=2: 36x12; P=1: 34x10
    __shared__ uint4 sA[TIH*TIW*5];                 // P=2: 34.6 KB
    __shared__ uint4 sW4[9*2*64];                   // 18 KB
    const int tid = threadIdx.x;
    const int lane = tid & 63, wv = tid >> 6;
    const int x0 = blockIdx.x*TW, y0 = blockIdx.y*TH, bz = blockIdx.z;
    const _Float16* inB = in + (size_t)bz*VOX*32;

    {   // weight fragments: lane&15 -> oc (A-operand row), (lane>>4)*8+j -> ic
        _Float16* sWh = (_Float16*)sW4;
        for (int idx = tid; idx < 9216; idx += 256){
            int j = idx & 7, ln = (idx>>3) & 63, rest = idx >> 9;
            int t = rest >> 1, nt = rest & 1;
            int ic = (ln>>4)*8 + j, oc = nt*16 + (ln&15);
            sWh[idx] = (_Float16)W32[((size_t)oc*32 + ic)*9 + t];
        }
    }
    // stage input tile (halo, zero-padded), 16B units
    for (int u = tid; u < TIH*TIW*4; u += 256){
        int g = u & 3;
        int pxr = u >> 2;
        int px = pxr % TIW, r = pxr / TIW;
        int gy = y0 - P + r, gx = x0 - P + px;
        uint4 v = make_uint4(0,0,0,0);
        if ((unsigned)gy < 512u && (unsigned)gx < 512u)
            v = *(const uint4*)(inB + (((size_t)gy*512 + gx)*32 + g*8));
        sA[(r*TIW + px)*5 + g] = v;
    }
    __syncthreads();

    const f16x8* pA = (const f16x8*)sA;
    const f16x8* pW = (const f16x8*)sW4;
    const int aoff = (lane&15)*5 + (lane>>4);
    const int rowbase = wv*2;                       // wave -> 2 rows x 32 px

    f32x4 acc[4][2];
    #pragma unroll
    for (int m=0;m<4;m++){ acc[m][0]=(f32x4)0.f; acc[m][1]=(f32x4)0.f; }

    #pragma unroll
    for (int t=0;t<9;t++){
        const int ky = t/3, kx = t%3;
        f16x8 b0 = pW[(t*2+0)*64 + lane];
        f16x8 b1 = pW[(t*2+1)*64 + lane];
        #pragma unroll
        for (int m=0;m<4;m++){
            int r = rowbase + (m>>1) + ky*P;
            int pxb = (m&1)*16 + kx*P;
            f16x8 a = pA[(r*TIW + pxb)*5 + aoff];
            // swapped: W as A-operand, input as B-operand -> D[oc][px]
            acc[m][0] = __builtin_amdgcn_mfma_f32_16x16x32_f16(b0, a, acc[m][0], 0,0,0);
            acc[m][1] = __builtin_amdgcn_mfma_f32_16x16x32_f16(b1, a, acc[m][1], 0,0,0);
        }
    }

    // epilogue: D row = oc = n*16 + (lane>>4)*4 + r ; col = px-offset = lane&15
    float bn[2][4], sn[2][4], tn[2][4];
    #pragma unroll
    for (int n=0;n<2;n++){
        int ocb = n*16 + (lane>>4)*4;
        #pragma unroll
        for (int r=0;r<4;r++){ bn[n][r]=bb[ocb+r]; sn[n][r]=ss[ocb+r]; tn[n][r]=tt[ocb+r]; }
    }
    _Float16* outB = out + (size_t)bz*VOX*32;
    #pragma unroll
    for (int m=0;m<4;m++){
        int y  = y0 + rowbase + (m>>1);
        int px = x0 + (m&1)*16 + (lane&15);
        #pragma unroll
        for (int n=0;n<2;n++){
            unsigned h[4];
            #pragma unroll
            for (int r=0;r<4;r++){
                float v = relu_(fmaf(acc[m][n][r] + bn[n][r], sn[n][r], tn[n][r]));
                h[r] = (unsigned)__half_as_ushort(__float2half_rn(v));
            }
            uint2 val = make_uint2(h[0] | (h[1]<<16), h[2] | (h[3]<<16));
            *(uint2*)(outB + ((size_t)y*512 + px)*32 + n*16 + (lane>>4)*4) = val;
        }
    }
}

// ---------------- bilinear sample (NHWC fp16 grid) + add w3[:,32:]@point1 + b3
__global__ void kFinal(const int* __restrict__ bid, const float* __restrict__ pts,
                       const _Float16* __restrict__ gridH,
                       const float* __restrict__ w3, const float* __restrict__ b3,
                       float* __restrict__ outp)
{
    int i = blockIdx.x*256 + threadIdx.x;
    if (i >= N_PTS) return;
    float px = pts[i], py = pts[N_PTS+i];
    int b = bid[i];
    float ix = px*512.0f - 1.0f;
    float iy = py*512.0f - 1.0f + (float)(b*512);
    float x0f = floorf(ix), y0f = floorf(iy);
    float wx = ix - x0f, wy = iy - y0f;
    int x0 = (int)x0f, y0 = (int)y0f;

    float p1[32];
    #pragma unroll
    for (int c=0;c<32;c++) p1[c] = 0.f;
    #pragma unroll
    for (int t=0;t<4;t++){
        int yi = y0 + (t>>1);
        int xi = x0 + (t&1);
        if (yi < 0 || yi >= BATCHN*YN || xi < 0 || xi >= XN) continue;
        float wgt = ((t>>1)? wy : 1.0f-wy) * ((t&1)? wx : 1.0f-wx);
        const uint4* tp = (const uint4*)(gridH + ((size_t)yi*XN + xi)*32);
        #pragma unroll
        for (int q=0;q<4;q++){
            uint4 v = tp[q];
            const unsigned int* vu = (const unsigned int*)&v;
            #pragma unroll
            for (int e=0;e<4;e++){
                float lo = __half2float(__ushort_as_half((unsigned short)(vu[e] & 0xFFFF)));
                float hi = __half2float(__ushort_as_half((unsigned short)(vu[e] >> 16)));
                p1[q*8 + e*2 + 0] = fmaf(wgt, lo, p1[q*8 + e*2 + 0]);
                p1[q*8 + e*2 + 1] = fmaf(wgt, hi, p1[q*8 + e*2 + 1]);
            }
        }
    }

    #pragma unroll
    for (int k=0;k<20;k++){
        float a = outp[(size_t)k*N_PTS + i] + b3[k];
        #pragma unroll
        for (int c=0;c<32;c++) a = fmaf(w3[k*64+32+c], p1[c], a);
        outp[(size_t)k*N_PTS + i] = a;
    }
}

extern "C" void kernel_launch(void* const* d_in, const int* in_sizes, int n_in,
                              void* d_out, int out_size, void* d_ws, size_t ws_size,
                              hipStream_t stream)
{
    const int*   bid = (const int*)  d_in[0];
    const float* pts = (const float*)d_in[1];
    const float* w0  = (const float*)d_in[3];
    const float* b0  = (const float*)d_in[4];
    const float* s0  = (const float*)d_in[5];
    const float* t0  = (const float*)d_in[6];
    const float* w1  = (const float*)d_in[7];
    const float* b1  = (const float*)d_in[8];
    const float* s1  = (const float*)d_in[9];
    const float* t1  = (const float*)d_in[10];
    const float* wv0 = (const float*)d_in[11];
    const float* bv0 = (const float*)d_in[12];
    const float* sv0 = (const float*)d_in[13];
    const float* tv0 = (const float*)d_in[14];
    const float* wv1 = (const float*)d_in[15];
    const float* bv1 = (const float*)d_in[16];
    const float* sv1 = (const float*)d_in[17];
    const float* tv1 = (const float*)d_in[18];
    const float* w2  = (const float*)d_in[19];
    const float* b2  = (const float*)d_in[20];
    const float* s2  = (const float*)d_in[21];
    const float* t2  = (const float*)d_in[22];
    const float* w2d = (const float*)d_in[23];
    const float* b2d = (const float*)d_in[24];
    const float* s2d = (const float*)d_in[25];
    const float* t2d = (const float*)d_in[26];
    const float* w3  = (const float*)d_in[27];
    const float* b3  = (const float*)d_in[28];

    const size_t MB = 1024*1024;
    const size_t NEED = 192*MB;
    if (ws_size < NEED){
        kDiag<<<512,256,0,stream>>>((float*)d_out, out_size, (float)(ws_size>>20));
        return;
    }

    char* ws = (char*)d_ws;
    u64*      gridV    = (u64*)ws;                        // 64 MiB NHWC fp16 (conv ping)
    _Float16* ping     = (_Float16*)ws;
    _Float16* pong     = (_Float16*)(ws + 64*MB);         // 64 MiB (conv pong)
    u64*      seg0     = (u64*)(ws + 64*MB);              // 32 MiB, alias pong (dead before conv0)
    u64*      seg1     = (u64*)(ws + 96*MB);              // 32 MiB, alias pong
    unsigned* offs     = (unsigned*)(ws + 128*MB);        // 4 MiB hist/offsets
    unsigned* partials = (unsigned*)(ws + 132*MB);        // 16 KiB
    unsigned* order    = (unsigned*)(ws + 133*MB);        // 1.6 MiB
    int*      gids     = (int*)(ws + 135*MB);             // 1.6 MiB
    u64*      obufA    = (u64*)(ws + 137*MB);             // 12.8 MiB [pt][16ch fp16]
    u64*      obufB    = (u64*)(ws + 150*MB);             // 12.8 MiB
    u64*      pbuf     = (u64*)(ws + 163*MB);             // 25.6 MiB [pt][32ch fp16]

    // zero the histogram only
    kZero<<<256,256,0,stream>>>((float4*)offs, (int)(GRID_NUM*4/16));

    const int nb = (N_PTS + 255)/256;
    const int nv = GRID_NUM/256;                          // 4096

    kHist <<<nb,256,0,stream>>>(bid, pts, offs, gids);
    kScan1<<<nv,256,0,stream>>>(offs, partials);
    kScan2<<<1,256,0,stream>>>(partials);
    kScan3<<<nv,256,0,stream>>>(offs, partials);

    kA<<<nb,256,0,stream>>>(bid, pts, gids, w0,b0,s0,t0, w1,b1,s1,t1,
                            wv0,bv0,sv0,tv0, obufA, offs, order);
    kSegMax<<<nv,256,0,stream>>>(offs, order, obufA, seg0);
    kB<<<nb,256,0,stream>>>(gids, wv1,bv1,sv1,tv1, obufA, seg0, obufB);
    kSegMax<<<nv,256,0,stream>>>(offs, order, obufB, seg1);
    kC<<<nb,256,0,stream>>>(gids, w2,b2,s2,t2, w3, obufB, seg1, pbuf, (float*)d_out);
    kGridMax<<<nv,256,0,stream>>>(offs, order, pbuf, gridV);

    dim3 cgrid(XN/32, YN/8, BATCHN);
    convM<1><<<cgrid,256,0,stream>>>(ping, pong, w2d + 0*9216, b2d + 0,  s2d + 0,  t2d + 0);
    convM<2><<<cgrid,256,0,stream>>>(pong, ping, w2d + 1*9216, b2d + 32, s2d + 32, t2d + 32);
    convM<2><<<cgrid,256,0,stream>>>(ping, pong, w2d + 2*9216, b2d + 64, s2d + 64, t2d + 64);
    convM<2><<<cgrid,256,0,stream>>>(pong, ping, w2d + 3*9216, b2d + 96, s2d + 96, t2d + 96);

    kFinal<<<nb,256,0,stream>>>(bid, pts, ping, w3, b3, (float*)d_out);
}

// Round 10
// 356.672 us; speedup vs baseline: 2.0911x; 1.3537x over previous
//
#include <hip/hip_runtime.h>
#include <hip/hip_bf16.h>
#include <hip/hip_fp16.h>

#define N_PTS 400000
#define XN 512
#define YN 512
#define BATCHN 4
#define VOX (XN*YN)            // 262144
#define GRID_NUM (BATCHN*VOX)  // 1048576

typedef unsigned long long u64;
typedef __attribute__((ext_vector_type(8))) _Float16 f16x8;
typedef __attribute__((ext_vector_type(4))) float f32x4;

static __device__ __forceinline__ float relu_(float x){ return fmaxf(x, 0.0f); }
static __device__ __forceinline__ int voxel_id(float px, float py, int b){
    int xg = (int)floorf(px*512.0f);
    int yg = (int)floorf(py*512.0f);
    return b*VOX + yg*XN + xg;
}

// ---- packed 4x fp16 helpers (values >= 0; fp16 bits of non-neg order as u16)
static __device__ __forceinline__ u64 packh4(const float* v){
    u64 r = 0;
    #pragma unroll
    for (int j=0;j<4;j++){
        unsigned short h = __half_as_ushort(__float2half_rn(v[j]));
        r |= (u64)h << (16*j);
    }
    return r;
}
static __device__ __forceinline__ void unpackh4(u64 w, float* o){
    #pragma unroll
    for (int j=0;j<4;j++)
        o[j] = __half2float(__ushort_as_half((unsigned short)(w >> (16*j))));
}
static __device__ __forceinline__ u64 pkmax4(u64 a, u64 b){
    u64 r = 0;
    #pragma unroll
    for (int j=0;j<4;j++){
        u64 x = (a >> (16*j)) & 0xFFFFull;
        u64 y = (b >> (16*j)) & 0xFFFFull;
        r |= (x > y ? x : y) << (16*j);
    }
    return r;
}

// ---------------- zero scratch each launch
__global__ void kZero(float4* __restrict__ p, int n4){
    int i = blockIdx.x*256 + threadIdx.x;
    const float4 z = make_float4(0.f,0.f,0.f,0.f);
    for (; i < n4; i += gridDim.x*256) p[i] = z;
}

// ---------------- diagnostic: ws too small -> encode ws MiB in output
__global__ void kDiag(float* __restrict__ o, int n, float v){
    int i = blockIdx.x*256 + threadIdx.x;
    for (; i < n; i += gridDim.x*256) o[i] = v;
}

// ---------------- pre-convert conv weights to fragment-major fp16 (all 4 layers)
// layout per layer: [(t*2+nt)*64 + lane] x 8 halves; lane&15->oc%16, lane>>4->ic/8
__global__ void kWprep(const float* __restrict__ W32, _Float16* __restrict__ wf){
    int idx = blockIdx.x*256 + threadIdx.x;      // 4*9216
    if (idx >= 4*9216) return;
    int L = idx / 9216, r = idx % 9216;
    int j = r & 7, ln = (r>>3) & 63, rest = r >> 9;
    int t = rest >> 1, nt = rest & 1;
    int ic = (ln>>4)*8 + j, oc = nt*16 + (ln&15);
    wf[idx] = (_Float16)W32[(size_t)L*9216 + ((size_t)oc*32 + ic)*9 + t];
}

// ---------------- histogram of voxel ids (+ cache gids)
__global__ void kHist(const int* __restrict__ bid, const float* __restrict__ pts,
                      unsigned* __restrict__ offs, int* __restrict__ gids)
{
    int i = blockIdx.x*256 + threadIdx.x;
    if (i >= N_PTS) return;
    int gid = voxel_id(pts[i], pts[N_PTS+i], bid[i]);
    gids[i] = gid;
    atomicAdd(&offs[gid], 1u);
}

// ---------------- 3-kernel exclusive scan of offs[GRID_NUM]
__global__ void kScan1(unsigned* __restrict__ offs, unsigned* __restrict__ partials)
{
    __shared__ unsigned sa[256], sb[256];
    const int t = threadIdx.x;
    const int g = blockIdx.x*256 + t;
    unsigned v = offs[g];
    sa[t] = v;
    __syncthreads();
    unsigned* src = sa; unsigned* dst = sb;
    #pragma unroll
    for (int d=1; d<256; d<<=1){
        dst[t] = src[t] + ((t>=d) ? src[t-d] : 0u);
        __syncthreads();
        unsigned* tmp = src; src = dst; dst = tmp;
    }
    unsigned incl = src[t];
    offs[g] = incl - v;                    // exclusive within block
    if (t == 255) partials[blockIdx.x] = incl;
}
__global__ void kScan2(unsigned* __restrict__ partials)   // 4096 entries, 1 block
{
    __shared__ unsigned sa[256], sb[256];
    const int t = threadIdx.x;
    unsigned loc[16]; unsigned sum = 0;
    #pragma unroll
    for (int j=0;j<16;j++){ loc[j] = partials[t*16+j]; sum += loc[j]; }
    sa[t] = sum;
    __syncthreads();
    unsigned* src = sa; unsigned* dst = sb;
    #pragma unroll
    for (int d=1; d<256; d<<=1){
        dst[t] = src[t] + ((t>=d) ? src[t-d] : 0u);
        __syncthreads();
        unsigned* tmp = src; src = dst; dst = tmp;
    }
    unsigned run = src[t] - sum;           // exclusive base for this thread
    #pragma unroll
    for (int j=0;j<16;j++){ unsigned c = loc[j]; partials[t*16+j] = run; run += c; }
}
__global__ void kScan3(unsigned* __restrict__ offs, const unsigned* __restrict__ partials)
{
    int g = blockIdx.x*256 + threadIdx.x;
    offs[g] += partials[blockIdx.x];
}

// ---------------- Kernel A: MLPs -> obufA (packed fp16), place index in order[]
__global__ void kA(const int* __restrict__ bid, const float* __restrict__ pts,
                   const int* __restrict__ gids,
                   const float* __restrict__ w0, const float* __restrict__ b0,
                   const float* __restrict__ s0, const float* __restrict__ t0,
                   const float* __restrict__ w1, const float* __restrict__ b1,
                   const float* __restrict__ s1, const float* __restrict__ t1,
                   const float* __restrict__ wv0, const float* __restrict__ bv0,
                   const float* __restrict__ sv0, const float* __restrict__ tv0,
                   u64* __restrict__ obufA,
                   unsigned* __restrict__ offs, unsigned* __restrict__ order)
{
    int i = blockIdx.x*256 + threadIdx.x;
    if (i >= N_PTS) return;
    float p[6];
    #pragma unroll
    for (int r=0;r<6;r++) p[r] = pts[r*N_PTS+i];
    int xg = (int)floorf(p[0]*512.0f);
    int yg = (int)floorf(p[1]*512.0f);

    float h0[16];
    #pragma unroll
    for (int o=0;o<16;o++){
        float a = b0[o];
        #pragma unroll
        for (int k=0;k<6;k++) a = fmaf(w0[o*6+k], p[k], a);
        h0[o] = relu_(fmaf(a, s0[o], t0[o]));
    }
    float h1[16];
    #pragma unroll
    for (int o=0;o<16;o++){
        float a = b1[o];
        #pragma unroll
        for (int k=0;k<16;k++) a = fmaf(w1[o*16+k], h0[k], a);
        h1[o] = relu_(fmaf(a, s1[o], t1[o]));
    }
    float dx = p[0] - ((float)xg + 0.5f)*(1.0f/512.0f);
    float dy = p[1] - ((float)yg + 0.5f)*(1.0f/512.0f);
    float vv[16];
    #pragma unroll
    for (int o=0;o<16;o++){
        float a = bv0[o];
        #pragma unroll
        for (int k=0;k<16;k++) a = fmaf(wv0[o*18+k], h1[k], a);
        a = fmaf(wv0[o*18+16], dx, a);
        a = fmaf(wv0[o*18+17], dy, a);
        vv[o] = relu_(fmaf(a, sv0[o], tv0[o]));
    }
    u64* op = obufA + (size_t)i*4;
    #pragma unroll
    for (int q=0;q<4;q++) op[q] = packh4(&vv[q*4]);

    int gid = gids[i];
    unsigned pos = atomicAdd(&offs[gid], 1u);
    order[pos] = (unsigned)i;
}

// ---------------- per-voxel max over its points: 16ch (4 u64 words)
__global__ void kSegMax(const unsigned* __restrict__ offs, const unsigned* __restrict__ order,
                        const u64* __restrict__ src, u64* __restrict__ dst)
{
    int v = blockIdx.x*256 + threadIdx.x;
    unsigned s = v ? offs[v-1] : 0u;
    unsigned e = offs[v];
    if (e <= s) return;
    u64 m0=0,m1=0,m2=0,m3=0;
    for (unsigned p=s; p<e; ++p){
        const u64* q = src + (size_t)order[p]*4;
        m0 = pkmax4(m0, q[0]); m1 = pkmax4(m1, q[1]);
        m2 = pkmax4(m2, q[2]); m3 = pkmax4(m3, q[3]);
    }
    u64* d = dst + (size_t)v*4;
    d[0]=m0; d[1]=m1; d[2]=m2; d[3]=m3;
}

// ---------------- per-voxel max, 32ch (8 u64), write ALL voxels (zeros if empty) = NHWC fp16 grid
__global__ void kGridMax(const unsigned* __restrict__ offs, const unsigned* __restrict__ order,
                         const u64* __restrict__ src, u64* __restrict__ dst)
{
    int v = blockIdx.x*256 + threadIdx.x;
    unsigned s = v ? offs[v-1] : 0u;
    unsigned e = offs[v];
    u64 m[8];
    #pragma unroll
    for (int q=0;q<8;q++) m[q] = 0ull;
    for (unsigned p=s; p<e; ++p){
        const u64* q = src + (size_t)order[p]*8;
        #pragma unroll
        for (int j=0;j<8;j++) m[j] = pkmax4(m[j], q[j]);
    }
    u64* d = dst + (size_t)v*8;
    #pragma unroll
    for (int q=0;q<8;q++) d[q] = m[q];
}

// ---------------- Kernel B: concat(obufA, seg0[gid]) -> pconv(v1) -> obufB
__global__ void kB(const int* __restrict__ gids,
                   const float* __restrict__ w, const float* __restrict__ bb,
                   const float* __restrict__ ss, const float* __restrict__ tt,
                   const u64* __restrict__ obufA, const u64* __restrict__ seg0,
                   u64* __restrict__ obufB)
{
    int i = blockIdx.x*256 + threadIdx.x;
    if (i >= N_PTS) return;
    int gid = gids[i];
    float h[32];
    const u64* ap = obufA + (size_t)i*4;
    #pragma unroll
    for (int q=0;q<4;q++) unpackh4(ap[q], &h[q*4]);
    const u64* sp = seg0 + (size_t)gid*4;
    #pragma unroll
    for (int q=0;q<4;q++) unpackh4(sp[q], &h[16+q*4]);

    float o[16];
    #pragma unroll
    for (int c=0;c<16;c++){
        float a = bb[c];
        #pragma unroll
        for (int k=0;k<32;k++) a = fmaf(w[c*32+k], h[k], a);
        o[c] = relu_(fmaf(a, ss[c], tt[c]));
    }
    u64* op = obufB + (size_t)i*4;
    #pragma unroll
    for (int q=0;q<4;q++) op[q] = packh4(&o[q*4]);
}

// ---------------- Kernel C: concat(obufB, seg1[gid]) -> pconv(w2)=point0 -> pbuf,
//                  pre-project through w3[:, :32] into d_out
__global__ void kC(const int* __restrict__ gids,
                   const float* __restrict__ w, const float* __restrict__ bb,
                   const float* __restrict__ ss, const float* __restrict__ tt,
                   const float* __restrict__ w3,
                   const u64* __restrict__ obufB, const u64* __restrict__ seg1,
                   u64* __restrict__ pbuf, float* __restrict__ outp)
{
    int i = blockIdx.x*256 + threadIdx.x;
    if (i >= N_PTS) return;
    int gid = gids[i];
    float h[32];
    const u64* ap = obufB + (size_t)i*4;
    #pragma unroll
    for (int q=0;q<4;q++) unpackh4(ap[q], &h[q*4]);
    const u64* sp = seg1 + (size_t)gid*4;
    #pragma unroll
    for (int q=0;q<4;q++) unpackh4(sp[q], &h[16+q*4]);

    float p0v[32];
    #pragma unroll
    for (int c=0;c<32;c++){
        float a = bb[c];
        #pragma unroll
        for (int k=0;k<32;k++) a = fmaf(w[c*32+k], h[k], a);
        p0v[c] = relu_(fmaf(a, ss[c], tt[c]));
    }
    u64* pp = pbuf + (size_t)i*8;
    #pragma unroll
    for (int q=0;q<8;q++) pp[q] = packh4(&p0v[q*4]);
    #pragma unroll
    for (int k=0;k<20;k++){
        float a = 0.f;
        #pragma unroll
        for (int c=0;c<32;c++) a = fmaf(w3[k*64+c], p0v[c], a);
        outp[(size_t)k*N_PTS+i] = a;
    }
}

// ---------------- dilated 3x3 conv + BN + ReLU via MFMA implicit GEMM
// NHWC fp16. LDS-staged A (stride-5-uint4 pad); weights DIRECT from prepped
// fragment buffer (coalesced 16B/lane, L1-resident: same 18KB reused by every block).
// Swapped operands: mfma(W,A) -> D[oc][px] -> packed uint2 stores (64MB exact).
template<int P>
__global__ __launch_bounds__(256,4) void convM(
    const _Float16* __restrict__ in, _Float16* __restrict__ out,
    const f16x8* __restrict__ wfrag, const float* __restrict__ bb,
    const float* __restrict__ ss, const float* __restrict__ tt)
{
    constexpr int TW = 32, TH = 8;
    constexpr int TIW = TW + 2*P, TIH = TH + 2*P;   // P=2: 36x12; P=1: 34x10
    __shared__ uint4 sA[TIH*TIW*5];                 // P=2: 34.6 KB -> 4 blocks/CU
    const int tid = threadIdx.x;
    const int lane = tid & 63, wv = tid >> 6;
    const int x0 = blockIdx.x*TW, y0 = blockIdx.y*TH, bz = blockIdx.z;
    const _Float16* inB = in + (size_t)bz*VOX*32;

    // stage input tile (halo, zero-padded), 16B units
    for (int u = tid; u < TIH*TIW*4; u += 256){
        int g = u & 3;
        int pxr = u >> 2;
        int px = pxr % TIW, r = pxr / TIW;
        int gy = y0 - P + r, gx = x0 - P + px;
        uint4 v = make_uint4(0,0,0,0);
        if ((unsigned)gy < 512u && (unsigned)gx < 512u)
            v = *(const uint4*)(inB + (((size_t)gy*512 + gx)*32 + g*8));
        sA[(r*TIW + px)*5 + g] = v;
    }
    __syncthreads();

    const f16x8* pA = (const f16x8*)sA;
    const int aoff = (lane&15)*5 + (lane>>4);
    const int rowbase = wv*2;                       // wave -> 2 rows x 32 px

    f32x4 acc[4][2];
    #pragma unroll
    for (int m=0;m<4;m++){ acc[m][0]=(f32x4)0.f; acc[m][1]=(f32x4)0.f; }

    #pragma unroll
    for (int t=0;t<9;t++){
        const int ky = t/3, kx = t%3;
        f16x8 b0 = wfrag[(t*2+0)*64 + lane];        // L1-broadcast global read
        f16x8 b1 = wfrag[(t*2+1)*64 + lane];
        #pragma unroll
        for (int m=0;m<4;m++){
            int r = rowbase + (m>>1) + ky*P;
            int pxb = (m&1)*16 + kx*P;
            f16x8 a = pA[(r*TIW + pxb)*5 + aoff];
            acc[m][0] = __builtin_amdgcn_mfma_f32_16x16x32_f16(b0, a, acc[m][0], 0,0,0);
            acc[m][1] = __builtin_amdgcn_mfma_f32_16x16x32_f16(b1, a, acc[m][1], 0,0,0);
        }
    }

    // epilogue: D row = oc = n*16 + (lane>>4)*4 + r ; col = px-offset = lane&15
    float bn[2][4], sn[2][4], tn[2][4];
    #pragma unroll
    for (int n=0;n<2;n++){
        int ocb = n*16 + (lane>>4)*4;
        #pragma unroll
        for (int r=0;r<4;r++){ bn[n][r]=bb[ocb+r]; sn[n][r]=ss[ocb+r]; tn[n][r]=tt[ocb+r]; }
    }
    _Float16* outB = out + (size_t)bz*VOX*32;
    #pragma unroll
    for (int m=0;m<4;m++){
        int y  = y0 + rowbase + (m>>1);
        int px = x0 + (m&1)*16 + (lane&15);
        #pragma unroll
        for (int n=0;n<2;n++){
            unsigned h[4];
            #pragma unroll
            for (int r=0;r<4;r++){
                float v = relu_(fmaf(acc[m][n][r] + bn[n][r], sn[n][r], tn[n][r]));
                h[r] = (unsigned)__half_as_ushort(__float2half_rn(v));
            }
            uint2 val = make_uint2(h[0] | (h[1]<<16), h[2] | (h[3]<<16));
            *(uint2*)(outB + ((size_t)y*512 + px)*32 + n*16 + (lane>>4)*4) = val;
        }
    }
}

// ---------------- bilinear sample (NHWC fp16 grid) + add w3[:,32:]@point1 + b3
__global__ void kFinal(const int* __restrict__ bid, const float* __restrict__ pts,
                       const _Float16* __restrict__ gridH,
                       const float* __restrict__ w3, const float* __restrict__ b3,
                       float* __restrict__ outp)
{
    int i = blockIdx.x*256 + threadIdx.x;
    if (i >= N_PTS) return;
    float px = pts[i], py = pts[N_PTS+i];
    int b = bid[i];
    float ix = px*512.0f - 1.0f;
    float iy = py*512.0f - 1.0f + (float)(b*512);
    float x0f = floorf(ix), y0f = floorf(iy);
    float wx = ix - x0f, wy = iy - y0f;
    int x0 = (int)x0f, y0 = (int)y0f;

    float p1[32];
    #pragma unroll
    for (int c=0;c<32;c++) p1[c] = 0.f;
    #pragma unroll
    for (int t=0;t<4;t++){
        int yi = y0 + (t>>1);
        int xi = x0 + (t&1);
        if (yi < 0 || yi >= BATCHN*YN || xi < 0 || xi >= XN) continue;
        float wgt = ((t>>1)? wy : 1.0f-wy) * ((t&1)? wx : 1.0f-wx);
        const uint4* tp = (const uint4*)(gridH + ((size_t)yi*XN + xi)*32);
        #pragma unroll
        for (int q=0;q<4;q++){
            uint4 v = tp[q];
            const unsigned int* vu = (const unsigned int*)&v;
            #pragma unroll
            for (int e=0;e<4;e++){
                float lo = __half2float(__ushort_as_half((unsigned short)(vu[e] & 0xFFFF)));
                float hi = __half2float(__ushort_as_half((unsigned short)(vu[e] >> 16)));
                p1[q*8 + e*2 + 0] = fmaf(wgt, lo, p1[q*8 + e*2 + 0]);
                p1[q*8 + e*2 + 1] = fmaf(wgt, hi, p1[q*8 + e*2 + 1]);
            }
        }
    }

    #pragma unroll
    for (int k=0;k<20;k++){
        float a = outp[(size_t)k*N_PTS + i] + b3[k];
        #pragma unroll
        for (int c=0;c<32;c++) a = fmaf(w3[k*64+32+c], p1[c], a);
        outp[(size_t)k*N_PTS + i] = a;
    }
}

extern "C" void kernel_launch(void* const* d_in, const int* in_sizes, int n_in,
                              void* d_out, int out_size, void* d_ws, size_t ws_size,
                              hipStream_t stream)
{
    const int*   bid = (const int*)  d_in[0];
    const float* pts = (const float*)d_in[1];
    const float* w0  = (const float*)d_in[3];
    const float* b0  = (const float*)d_in[4];
    const float* s0  = (const float*)d_in[5];
    const float* t0  = (const float*)d_in[6];
    const float* w1  = (const float*)d_in[7];
    const float* b1  = (const float*)d_in[8];
    const float* s1  = (const float*)d_in[9];
    const float* t1  = (const float*)d_in[10];
    const float* wv0 = (const float*)d_in[11];
    const float* bv0 = (const float*)d_in[12];
    const float* sv0 = (const float*)d_in[13];
    const float* tv0 = (const float*)d_in[14];
    const float* wv1 = (const float*)d_in[15];
    const float* bv1 = (const float*)d_in[16];
    const float* sv1 = (const float*)d_in[17];
    const float* tv1 = (const float*)d_in[18];
    const float* w2  = (const float*)d_in[19];
    const float* b2  = (const float*)d_in[20];
    const float* s2  = (const float*)d_in[21];
    const float* t2  = (const float*)d_in[22];
    const float* w2d = (const float*)d_in[23];
    const float* b2d = (const float*)d_in[24];
    const float* s2d = (const float*)d_in[25];
    const float* t2d = (const float*)d_in[26];
    const float* w3  = (const float*)d_in[27];
    const float* b3  = (const float*)d_in[28];

    const size_t MB = 1024*1024;
    const size_t NEED = 192*MB;
    if (ws_size < NEED){
        kDiag<<<512,256,0,stream>>>((float*)d_out, out_size, (float)(ws_size>>20));
        return;
    }

    char* ws = (char*)d_ws;
    u64*      gridV    = (u64*)ws;                        // 64 MiB NHWC fp16 (conv ping)
    _Float16* ping     = (_Float16*)ws;
    _Float16* pong     = (_Float16*)(ws + 64*MB);         // 64 MiB (conv pong)
    u64*      seg0     = (u64*)(ws + 64*MB);              // 32 MiB, alias pong (dead before conv0)
    u64*      seg1     = (u64*)(ws + 96*MB);              // 32 MiB, alias pong
    unsigned* offs     = (unsigned*)(ws + 128*MB);        // 4 MiB hist/offsets
    unsigned* partials = (unsigned*)(ws + 132*MB);        // 16 KiB
    unsigned* order    = (unsigned*)(ws + 133*MB);        // 1.6 MiB
    int*      gids     = (int*)(ws + 135*MB);             // 1.6 MiB
    u64*      obufA    = (u64*)(ws + 137*MB);             // 12.8 MiB [pt][16ch fp16]
    u64*      obufB    = (u64*)(ws + 150*MB);             // 12.8 MiB
    u64*      pbuf     = (u64*)(ws + 163*MB);             // 25.6 MiB [pt][32ch fp16]
    _Float16* wfrag    = (_Float16*)(ws + 189*MB);        // 72 KiB prepped weights

    // zero the histogram only
    kZero<<<256,256,0,stream>>>((float4*)offs, (int)(GRID_NUM*4/16));
    kWprep<<<144,256,0,stream>>>(w2d, wfrag);

    const int nb = (N_PTS + 255)/256;
    const int nv = GRID_NUM/256;                          // 4096

    kHist <<<nb,256,0,stream>>>(bid, pts, offs, gids);
    kScan1<<<nv,256,0,stream>>>(offs, partials);
    kScan2<<<1,256,0,stream>>>(partials);
    kScan3<<<nv,256,0,stream>>>(offs, partials);

    kA<<<nb,256,0,stream>>>(bid, pts, gids, w0,b0,s0,t0, w1,b1,s1,t1,
                            wv0,bv0,sv0,tv0, obufA, offs, order);
    kSegMax<<<nv,256,0,stream>>>(offs, order, obufA, seg0);
    kB<<<nb,256,0,stream>>>(gids, wv1,bv1,sv1,tv1, obufA, seg0, obufB);
    kSegMax<<<nv,256,0,stream>>>(offs, order, obufB, seg1);
    kC<<<nb,256,0,stream>>>(gids, w2,b2,s2,t2, w3, obufB, seg1, pbuf, (float*)d_out);
    kGridMax<<<nv,256,0,stream>>>(offs, order, pbuf, gridV);

    dim3 cgrid(XN/32, YN/8, BATCHN);
    const f16x8* wf = (const f16x8*)wfrag;
    convM<1><<<cgrid,256,0,stream>>>(ping, pong, wf + 0*1152, b2d + 0,  s2d + 0,  t2d + 0);
    convM<2><<<cgrid,256,0,stream>>>(pong, ping, wf + 1*1152, b2d + 32, s2d + 32, t2d + 32);
    convM<2><<<cgrid,256,0,stream>>>(ping, pong, wf + 2*1152, b2d + 64, s2d + 64, t2d + 64);
    convM<2><<<cgrid,256,0,stream>>>(pong, ping, wf + 3*1152, b2d + 96, s2d + 96, t2d + 96);

    kFinal<<<nb,256,0,stream>>>(bid, pts, ping, w3, b3, (float*)d_out);
}

// Round 11
// 344.077 us; speedup vs baseline: 2.1677x; 1.0366x over previous
//
#include <hip/hip_runtime.h>
#include <hip/hip_bf16.h>
#include <hip/hip_fp16.h>

#define N_PTS 400000
#define XN 512
#define YN 512
#define BATCHN 4
#define VOX (XN*YN)            // 262144
#define GRID_NUM (BATCHN*VOX)  // 1048576

typedef unsigned long long u64;
typedef __attribute__((ext_vector_type(8))) _Float16 f16x8;
typedef __attribute__((ext_vector_type(4))) float f32x4;

static __device__ __forceinline__ float relu_(float x){ return fmaxf(x, 0.0f); }
static __device__ __forceinline__ int voxel_id(float px, float py, int b){
    int xg = (int)floorf(px*512.0f);
    int yg = (int)floorf(py*512.0f);
    return b*VOX + yg*XN + xg;
}

// ---- packed 4x fp16 helpers (values >= 0; fp16 bits of non-neg order as u16)
static __device__ __forceinline__ u64 packh4(const float* v){
    u64 r = 0;
    #pragma unroll
    for (int j=0;j<4;j++){
        unsigned short h = __half_as_ushort(__float2half_rn(v[j]));
        r |= (u64)h << (16*j);
    }
    return r;
}
static __device__ __forceinline__ void unpackh4(u64 w, float* o){
    #pragma unroll
    for (int j=0;j<4;j++)
        o[j] = __half2float(__ushort_as_half((unsigned short)(w >> (16*j))));
}
static __device__ __forceinline__ u64 pkmax4(u64 a, u64 b){
    u64 r = 0;
    #pragma unroll
    for (int j=0;j<4;j++){
        u64 x = (a >> (16*j)) & 0xFFFFull;
        u64 y = (b >> (16*j)) & 0xFFFFull;
        r |= (x > y ? x : y) << (16*j);
    }
    return r;
}

// ---------------- zero scratch each launch
__global__ void kZero(float4* __restrict__ p, int n4){
    int i = blockIdx.x*256 + threadIdx.x;
    const float4 z = make_float4(0.f,0.f,0.f,0.f);
    for (; i < n4; i += gridDim.x*256) p[i] = z;
}

// ---------------- diagnostic: ws too small -> encode ws MiB in output
__global__ void kDiag(float* __restrict__ o, int n, float v){
    int i = blockIdx.x*256 + threadIdx.x;
    for (; i < n; i += gridDim.x*256) o[i] = v;
}

// ---------------- pre-convert conv weights to fragment-major fp16 (all 4 layers)
__global__ void kWprep(const float* __restrict__ W32, _Float16* __restrict__ wf){
    int idx = blockIdx.x*256 + threadIdx.x;      // 4*9216
    if (idx >= 4*9216) return;
    int L = idx / 9216, r = idx % 9216;
    int j = r & 7, ln = (r>>3) & 63, rest = r >> 9;
    int t = rest >> 1, nt = rest & 1;
    int ic = (ln>>4)*8 + j, oc = nt*16 + (ln&15);
    wf[idx] = (_Float16)W32[(size_t)L*9216 + ((size_t)oc*32 + ic)*9 + t];
}

// ---------------- histogram of voxel ids (+ cache gids)
__global__ void kHist(const int* __restrict__ bid, const float* __restrict__ pts,
                      unsigned* __restrict__ offs, int* __restrict__ gids)
{
    int i = blockIdx.x*256 + threadIdx.x;
    if (i >= N_PTS) return;
    int gid = voxel_id(pts[i], pts[N_PTS+i], bid[i]);
    gids[i] = gid;
    atomicAdd(&offs[gid], 1u);
}

// ---------------- 3-kernel exclusive scan of offs[GRID_NUM]
__global__ void kScan1(unsigned* __restrict__ offs, unsigned* __restrict__ partials)
{
    __shared__ unsigned sa[256], sb[256];
    const int t = threadIdx.x;
    const int g = blockIdx.x*256 + t;
    unsigned v = offs[g];
    sa[t] = v;
    __syncthreads();
    unsigned* src = sa; unsigned* dst = sb;
    #pragma unroll
    for (int d=1; d<256; d<<=1){
        dst[t] = src[t] + ((t>=d) ? src[t-d] : 0u);
        __syncthreads();
        unsigned* tmp = src; src = dst; dst = tmp;
    }
    unsigned incl = src[t];
    offs[g] = incl - v;                    // exclusive within block
    if (t == 255) partials[blockIdx.x] = incl;
}
__global__ void kScan2(unsigned* __restrict__ partials)   // 4096 entries, 1 block
{
    __shared__ unsigned sa[256], sb[256];
    const int t = threadIdx.x;
    unsigned loc[16]; unsigned sum = 0;
    #pragma unroll
    for (int j=0;j<16;j++){ loc[j] = partials[t*16+j]; sum += loc[j]; }
    sa[t] = sum;
    __syncthreads();
    unsigned* src = sa; unsigned* dst = sb;
    #pragma unroll
    for (int d=1; d<256; d<<=1){
        dst[t] = src[t] + ((t>=d) ? src[t-d] : 0u);
        __syncthreads();
        unsigned* tmp = src; src = dst; dst = tmp;
    }
    unsigned run = src[t] - sum;           // exclusive base for this thread
    #pragma unroll
    for (int j=0;j<16;j++){ unsigned c = loc[j]; partials[t*16+j] = run; run += c; }
}
__global__ void kScan3(unsigned* __restrict__ offs, const unsigned* __restrict__ partials)
{
    int g = blockIdx.x*256 + threadIdx.x;
    offs[g] += partials[blockIdx.x];
}

// ---------------- Kernel A: MLPs -> obufA at SORTED position; record sGid + inv
__global__ void kA(const int* __restrict__ bid, const float* __restrict__ pts,
                   const int* __restrict__ gids,
                   const float* __restrict__ w0, const float* __restrict__ b0,
                   const float* __restrict__ s0, const float* __restrict__ t0,
                   const float* __restrict__ w1, const float* __restrict__ b1,
                   const float* __restrict__ s1, const float* __restrict__ t1,
                   const float* __restrict__ wv0, const float* __restrict__ bv0,
                   const float* __restrict__ sv0, const float* __restrict__ tv0,
                   u64* __restrict__ obufA, unsigned* __restrict__ offs,
                   int* __restrict__ sGid, unsigned* __restrict__ inv)
{
    int i = blockIdx.x*256 + threadIdx.x;
    if (i >= N_PTS) return;
    float p[6];
    #pragma unroll
    for (int r=0;r<6;r++) p[r] = pts[r*N_PTS+i];
    int xg = (int)floorf(p[0]*512.0f);
    int yg = (int)floorf(p[1]*512.0f);

    float h0[16];
    #pragma unroll
    for (int o=0;o<16;o++){
        float a = b0[o];
        #pragma unroll
        for (int k=0;k<6;k++) a = fmaf(w0[o*6+k], p[k], a);
        h0[o] = relu_(fmaf(a, s0[o], t0[o]));
    }
    float h1[16];
    #pragma unroll
    for (int o=0;o<16;o++){
        float a = b1[o];
        #pragma unroll
        for (int k=0;k<16;k++) a = fmaf(w1[o*16+k], h0[k], a);
        h1[o] = relu_(fmaf(a, s1[o], t1[o]));
    }
    float dx = p[0] - ((float)xg + 0.5f)*(1.0f/512.0f);
    float dy = p[1] - ((float)yg + 0.5f)*(1.0f/512.0f);
    float vv[16];
    #pragma unroll
    for (int o=0;o<16;o++){
        float a = bv0[o];
        #pragma unroll
        for (int k=0;k<16;k++) a = fmaf(wv0[o*18+k], h1[k], a);
        a = fmaf(wv0[o*18+16], dx, a);
        a = fmaf(wv0[o*18+17], dy, a);
        vv[o] = relu_(fmaf(a, sv0[o], tv0[o]));
    }
    int gid = gids[i];
    unsigned pos = atomicAdd(&offs[gid], 1u);
    u64* op = obufA + (size_t)pos*4;
    #pragma unroll
    for (int q=0;q<4;q++) op[q] = packh4(&vv[q*4]);
    sGid[pos] = gid;
    inv[i] = pos;
}

// ---------------- per-voxel max over its CONTIGUOUS segment: 16ch
__global__ void kSegMax(const unsigned* __restrict__ offs,
                        const u64* __restrict__ src, u64* __restrict__ dst)
{
    int v = blockIdx.x*256 + threadIdx.x;
    unsigned s = v ? offs[v-1] : 0u;
    unsigned e = offs[v];
    if (e <= s) return;
    u64 m0=0,m1=0,m2=0,m3=0;
    for (unsigned p=s; p<e; ++p){
        const u64* q = src + (size_t)p*4;
        m0 = pkmax4(m0, q[0]); m1 = pkmax4(m1, q[1]);
        m2 = pkmax4(m2, q[2]); m3 = pkmax4(m3, q[3]);
    }
    u64* d = dst + (size_t)v*4;
    d[0]=m0; d[1]=m1; d[2]=m2; d[3]=m3;
}

// ---------------- per-voxel max over contiguous segment, 32ch; write ALL voxels
__global__ void kGridMax(const unsigned* __restrict__ offs,
                         const u64* __restrict__ src, u64* __restrict__ dst)
{
    int v = blockIdx.x*256 + threadIdx.x;
    unsigned s = v ? offs[v-1] : 0u;
    unsigned e = offs[v];
    u64 m[8];
    #pragma unroll
    for (int q=0;q<8;q++) m[q] = 0ull;
    for (unsigned p=s; p<e; ++p){
        const u64* q = src + (size_t)p*8;
        #pragma unroll
        for (int j=0;j<8;j++) m[j] = pkmax4(m[j], q[j]);
    }
    u64* d = dst + (size_t)v*8;
    #pragma unroll
    for (int q=0;q<8;q++) d[q] = m[q];
}

// ---------------- Kernel B: sorted j: concat(obufA[j], seg0[sGid[j]]) -> obufB[j]
__global__ void kB(const int* __restrict__ sGid,
                   const float* __restrict__ w, const float* __restrict__ bb,
                   const float* __restrict__ ss, const float* __restrict__ tt,
                   const u64* __restrict__ obufA, const u64* __restrict__ seg0,
                   u64* __restrict__ obufB)
{
    int j = blockIdx.x*256 + threadIdx.x;
    if (j >= N_PTS) return;
    int gid = sGid[j];
    float h[32];
    const u64* ap = obufA + (size_t)j*4;
    #pragma unroll
    for (int q=0;q<4;q++) unpackh4(ap[q], &h[q*4]);
    const u64* sp = seg0 + (size_t)gid*4;
    #pragma unroll
    for (int q=0;q<4;q++) unpackh4(sp[q], &h[16+q*4]);

    float o[16];
    #pragma unroll
    for (int c=0;c<16;c++){
        float a = bb[c];
        #pragma unroll
        for (int k=0;k<32;k++) a = fmaf(w[c*32+k], h[k], a);
        o[c] = relu_(fmaf(a, ss[c], tt[c]));
    }
    u64* op = obufB + (size_t)j*4;
    #pragma unroll
    for (int q=0;q<4;q++) op[q] = packh4(&o[q*4]);
}

// ---------------- Kernel C: sorted j: concat(obufB[j], seg1[sGid[j]]) -> pconv(w2) -> pbuf[j]
__global__ void kC(const int* __restrict__ sGid,
                   const float* __restrict__ w, const float* __restrict__ bb,
                   const float* __restrict__ ss, const float* __restrict__ tt,
                   const u64* __restrict__ obufB, const u64* __restrict__ seg1,
                   u64* __restrict__ pbuf)
{
    int j = blockIdx.x*256 + threadIdx.x;
    if (j >= N_PTS) return;
    int gid = sGid[j];
    float h[32];
    const u64* ap = obufB + (size_t)j*4;
    #pragma unroll
    for (int q=0;q<4;q++) unpackh4(ap[q], &h[q*4]);
    const u64* sp = seg1 + (size_t)gid*4;
    #pragma unroll
    for (int q=0;q<4;q++) unpackh4(sp[q], &h[16+q*4]);

    float p0v[32];
    #pragma unroll
    for (int c=0;c<32;c++){
        float a = bb[c];
        #pragma unroll
        for (int k=0;k<32;k++) a = fmaf(w[c*32+k], h[k], a);
        p0v[c] = relu_(fmaf(a, ss[c], tt[c]));
    }
    u64* pp = pbuf + (size_t)j*8;
    #pragma unroll
    for (int q=0;q<8;q++) pp[q] = packh4(&p0v[q*4]);
}

// ---------------- dilated 3x3 conv + BN + ReLU via MFMA implicit GEMM (unchanged r10)
template<int P>
__global__ __launch_bounds__(256,4) void convM(
    const _Float16* __restrict__ in, _Float16* __restrict__ out,
    const f16x8* __restrict__ wfrag, const float* __restrict__ bb,
    const float* __restrict__ ss, const float* __restrict__ tt)
{
    constexpr int TW = 32, TH = 8;
    constexpr int TIW = TW + 2*P, TIH = TH + 2*P;
    __shared__ uint4 sA[TIH*TIW*5];
    const int tid = threadIdx.x;
    const int lane = tid & 63, wv = tid >> 6;
    const int x0 = blockIdx.x*TW, y0 = blockIdx.y*TH, bz = blockIdx.z;
    const _Float16* inB = in + (size_t)bz*VOX*32;

    for (int u = tid; u < TIH*TIW*4; u += 256){
        int g = u & 3;
        int pxr = u >> 2;
        int px = pxr % TIW, r = pxr / TIW;
        int gy = y0 - P + r, gx = x0 - P + px;
        uint4 v = make_uint4(0,0,0,0);
        if ((unsigned)gy < 512u && (unsigned)gx < 512u)
            v = *(const uint4*)(inB + (((size_t)gy*512 + gx)*32 + g*8));
        sA[(r*TIW + px)*5 + g] = v;
    }
    __syncthreads();

    const f16x8* pA = (const f16x8*)sA;
    const int aoff = (lane&15)*5 + (lane>>4);
    const int rowbase = wv*2;

    f32x4 acc[4][2];
    #pragma unroll
    for (int m=0;m<4;m++){ acc[m][0]=(f32x4)0.f; acc[m][1]=(f32x4)0.f; }

    #pragma unroll
    for (int t=0;t<9;t++){
        const int ky = t/3, kx = t%3;
        f16x8 b0 = wfrag[(t*2+0)*64 + lane];
        f16x8 b1 = wfrag[(t*2+1)*64 + lane];
        #pragma unroll
        for (int m=0;m<4;m++){
            int r = rowbase + (m>>1) + ky*P;
            int pxb = (m&1)*16 + kx*P;
            f16x8 a = pA[(r*TIW + pxb)*5 + aoff];
            acc[m][0] = __builtin_amdgcn_mfma_f32_16x16x32_f16(b0, a, acc[m][0], 0,0,0);
            acc[m][1] = __builtin_amdgcn_mfma_f32_16x16x32_f16(b1, a, acc[m][1], 0,0,0);
        }
    }

    float bn[2][4], sn[2][4], tn[2][4];
    #pragma unroll
    for (int n=0;n<2;n++){
        int ocb = n*16 + (lane>>4)*4;
        #pragma unroll
        for (int r=0;r<4;r++){ bn[n][r]=bb[ocb+r]; sn[n][r]=ss[ocb+r]; tn[n][r]=tt[ocb+r]; }
    }
    _Float16* outB = out + (size_t)bz*VOX*32;
    #pragma unroll
    for (int m=0;m<4;m++){
        int y  = y0 + rowbase + (m>>1);
        int px = x0 + (m&1)*16 + (lane&15);
        #pragma unroll
        for (int n=0;n<2;n++){
            unsigned h[4];
            #pragma unroll
            for (int r=0;r<4;r++){
                float v = relu_(fmaf(acc[m][n][r] + bn[n][r], sn[n][r], tn[n][r]));
                h[r] = (unsigned)__half_as_ushort(__float2half_rn(v));
            }
            uint2 val = make_uint2(h[0] | (h[1]<<16), h[2] | (h[3]<<16));
            *(uint2*)(outB + ((size_t)y*512 + px)*32 + n*16 + (lane>>4)*4) = val;
        }
    }
}

// ---------------- bilinear sample + FULL 20x64 head (point0 via inv->pbuf) + b3
__global__ void kFinal(const int* __restrict__ bid, const float* __restrict__ pts,
                       const unsigned* __restrict__ inv, const u64* __restrict__ pbuf,
                       const _Float16* __restrict__ gridH,
                       const float* __restrict__ w3, const float* __restrict__ b3,
                       float* __restrict__ outp)
{
    int i = blockIdx.x*256 + threadIdx.x;
    if (i >= N_PTS) return;
    float px = pts[i], py = pts[N_PTS+i];
    int b = bid[i];

    float p0[32];
    const u64* pp = pbuf + (size_t)inv[i]*8;
    #pragma unroll
    for (int q=0;q<8;q++) unpackh4(pp[q], &p0[q*4]);

    float ix = px*512.0f - 1.0f;
    float iy = py*512.0f - 1.0f + (float)(b*512);
    float x0f = floorf(ix), y0f = floorf(iy);
    float wx = ix - x0f, wy = iy - y0f;
    int x0 = (int)x0f, y0 = (int)y0f;

    float p1[32];
    #pragma unroll
    for (int c=0;c<32;c++) p1[c] = 0.f;
    #pragma unroll
    for (int t=0;t<4;t++){
        int yi = y0 + (t>>1);
        int xi = x0 + (t&1);
        if (yi < 0 || yi >= BATCHN*YN || xi < 0 || xi >= XN) continue;
        float wgt = ((t>>1)? wy : 1.0f-wy) * ((t&1)? wx : 1.0f-wx);
        const uint4* tp = (const uint4*)(gridH + ((size_t)yi*XN + xi)*32);
        #pragma unroll
        for (int q=0;q<4;q++){
            uint4 v = tp[q];
            const unsigned int* vu = (const unsigned int*)&v;
            #pragma unroll
            for (int e=0;e<4;e++){
                float lo = __half2float(__ushort_as_half((unsigned short)(vu[e] & 0xFFFF)));
                float hi = __half2float(__ushort_as_half((unsigned short)(vu[e] >> 16)));
                p1[q*8 + e*2 + 0] = fmaf(wgt, lo, p1[q*8 + e*2 + 0]);
                p1[q*8 + e*2 + 1] = fmaf(wgt, hi, p1[q*8 + e*2 + 1]);
            }
        }
    }

    #pragma unroll
    for (int k=0;k<20;k++){
        float a = b3[k];
        #pragma unroll
        for (int c=0;c<32;c++) a = fmaf(w3[k*64+c], p0[c], a);
        #pragma unroll
        for (int c=0;c<32;c++) a = fmaf(w3[k*64+32+c], p1[c], a);
        outp[(size_t)k*N_PTS + i] = a;
    }
}

extern "C" void kernel_launch(void* const* d_in, const int* in_sizes, int n_in,
                              void* d_out, int out_size, void* d_ws, size_t ws_size,
                              hipStream_t stream)
{
    const int*   bid = (const int*)  d_in[0];
    const float* pts = (const float*)d_in[1];
    const float* w0  = (const float*)d_in[3];
    const float* b0  = (const float*)d_in[4];
    const float* s0  = (const float*)d_in[5];
    const float* t0  = (const float*)d_in[6];
    const float* w1  = (const float*)d_in[7];
    const float* b1  = (const float*)d_in[8];
    const float* s1  = (const float*)d_in[9];
    const float* t1  = (const float*)d_in[10];
    const float* wv0 = (const float*)d_in[11];
    const float* bv0 = (const float*)d_in[12];
    const float* sv0 = (const float*)d_in[13];
    const float* tv0 = (const float*)d_in[14];
    const float* wv1 = (const float*)d_in[15];
    const float* bv1 = (const float*)d_in[16];
    const float* sv1 = (const float*)d_in[17];
    const float* tv1 = (const float*)d_in[18];
    const float* w2  = (const float*)d_in[19];
    const float* b2  = (const float*)d_in[20];
    const float* s2  = (const float*)d_in[21];
    const float* t2  = (const float*)d_in[22];
    const float* w2d = (const float*)d_in[23];
    const float* b2d = (const float*)d_in[24];
    const float* s2d = (const float*)d_in[25];
    const float* t2d = (const float*)d_in[26];
    const float* w3  = (const float*)d_in[27];
    const float* b3  = (const float*)d_in[28];

    const size_t MB = 1024*1024;
    const size_t NEED = 192*MB;
    if (ws_size < NEED){
        kDiag<<<512,256,0,stream>>>((float*)d_out, out_size, (float)(ws_size>>20));
        return;
    }

    char* ws = (char*)d_ws;
    u64*      gridV    = (u64*)ws;                        // 64 MiB NHWC fp16 (conv ping)
    _Float16* ping     = (_Float16*)ws;
    _Float16* pong     = (_Float16*)(ws + 64*MB);         // 64 MiB (conv pong)
    u64*      seg0     = (u64*)(ws + 64*MB);              // 32 MiB, alias pong (dead before conv0)
    u64*      seg1     = (u64*)(ws + 96*MB);              // 32 MiB, alias pong
    unsigned* offs     = (unsigned*)(ws + 128*MB);        // 4 MiB hist/offsets
    unsigned* partials = (unsigned*)(ws + 132*MB);        // 16 KiB
    int*      sGid     = (int*)(ws + 133*MB);             // 1.6 MiB (sorted gid)
    int*      gids     = (int*)(ws + 135*MB);             // 1.6 MiB (original order)
    unsigned* inv      = (unsigned*)(ws + 137*MB);        // 1.6 MiB (orig -> sorted pos)
    u64*      obufA    = (u64*)(ws + 139*MB);             // 12.8 MiB sorted [pos][16ch]
    u64*      obufB    = (u64*)(ws + 152*MB);             // 12.8 MiB
    u64*      pbuf     = (u64*)(ws + 165*MB);             // 25.6 MiB sorted [pos][32ch]
    _Float16* wfrag    = (_Float16*)(ws + 191*MB);        // 72 KiB prepped weights

    // zero the histogram only
    kZero<<<256,256,0,stream>>>((float4*)offs, (int)(GRID_NUM*4/16));
    kWprep<<<144,256,0,stream>>>(w2d, wfrag);

    const int nb = (N_PTS + 255)/256;
    const int nv = GRID_NUM/256;                          // 4096

    kHist <<<nb,256,0,stream>>>(bid, pts, offs, gids);
    kScan1<<<nv,256,0,stream>>>(offs, partials);
    kScan2<<<1,256,0,stream>>>(partials);
    kScan3<<<nv,256,0,stream>>>(offs, partials);

    kA<<<nb,256,0,stream>>>(bid, pts, gids, w0,b0,s0,t0, w1,b1,s1,t1,
                            wv0,bv0,sv0,tv0, obufA, offs, sGid, inv);
    kSegMax<<<nv,256,0,stream>>>(offs, obufA, seg0);
    kB<<<nb,256,0,stream>>>(sGid, wv1,bv1,sv1,tv1, obufA, seg0, obufB);
    kSegMax<<<nv,256,0,stream>>>(offs, obufB, seg1);
    kC<<<nb,256,0,stream>>>(sGid, w2,b2,s2,t2, obufB, seg1, pbuf);
    kGridMax<<<nv,256,0,stream>>>(offs, pbuf, gridV);

    dim3 cgrid(XN/32, YN/8, BATCHN);
    const f16x8* wf = (const f16x8*)wfrag;
    convM<1><<<cgrid,256,0,stream>>>(ping, pong, wf + 0*1152, b2d + 0,  s2d + 0,  t2d + 0);
    convM<2><<<cgrid,256,0,stream>>>(pong, ping, wf + 1*1152, b2d + 32, s2d + 32, t2d + 32);
    convM<2><<<cgrid,256,0,stream>>>(ping, pong, wf + 2*1152, b2d + 64, s2d + 64, t2d + 64);
    convM<2><<<cgrid,256,0,stream>>>(pong, ping, wf + 3*1152, b2d + 96, s2d + 96, t2d + 96);

    kFinal<<<nb,256,0,stream>>>(bid, pts, inv, pbuf, ping, w3, b3, (float*)d_out);
}

// Round 12
// 343.720 us; speedup vs baseline: 2.1699x; 1.0010x over previous
//
#include <hip/hip_runtime.h>
#include <hip/hip_bf16.h>
#include <hip/hip_fp16.h>

#define N_PTS 400000
#define N_HALF 200000
#define XN 512
#define YN 512
#define BATCHN 4
#define VOX (XN*YN)            // 262144
#define GRID_NUM (BATCHN*VOX)  // 1048576

typedef unsigned long long u64;
typedef __attribute__((ext_vector_type(8))) _Float16 f16x8;
typedef __attribute__((ext_vector_type(4))) float f32x4;

static __device__ __forceinline__ float relu_(float x){ return fmaxf(x, 0.0f); }
static __device__ __forceinline__ int voxel_id(float px, float py, int b){
    int xg = (int)floorf(px*512.0f);
    int yg = (int)floorf(py*512.0f);
    return b*VOX + yg*XN + xg;
}

// ---- packed 4x fp16 helpers (values >= 0; fp16 bits of non-neg order as u16)
static __device__ __forceinline__ u64 packh4(const float* v){
    u64 r = 0;
    #pragma unroll
    for (int j=0;j<4;j++){
        unsigned short h = __half_as_ushort(__float2half_rn(v[j]));
        r |= (u64)h << (16*j);
    }
    return r;
}
static __device__ __forceinline__ void unpackh4(u64 w, float* o){
    #pragma unroll
    for (int j=0;j<4;j++)
        o[j] = __half2float(__ushort_as_half((unsigned short)(w >> (16*j))));
}
static __device__ __forceinline__ u64 pkmax4(u64 a, u64 b){
    u64 r = 0;
    #pragma unroll
    for (int j=0;j<4;j++){
        u64 x = (a >> (16*j)) & 0xFFFFull;
        u64 y = (b >> (16*j)) & 0xFFFFull;
        r |= (x > y ? x : y) << (16*j);
    }
    return r;
}

// ---------------- zero scratch each launch
__global__ void kZero(float4* __restrict__ p, int n4){
    int i = blockIdx.x*256 + threadIdx.x;
    const float4 z = make_float4(0.f,0.f,0.f,0.f);
    for (; i < n4; i += gridDim.x*256) p[i] = z;
}

// ---------------- diagnostic: ws too small -> encode ws MiB in output
__global__ void kDiag(float* __restrict__ o, int n, float v){
    int i = blockIdx.x*256 + threadIdx.x;
    for (; i < n; i += gridDim.x*256) o[i] = v;
}

// ---------------- pre-convert conv weights to fragment-major fp16 (all 4 layers)
__global__ void kWprep(const float* __restrict__ W32, _Float16* __restrict__ wf){
    int idx = blockIdx.x*256 + threadIdx.x;      // 4*9216
    if (idx >= 4*9216) return;
    int L = idx / 9216, r = idx % 9216;
    int j = r & 7, ln = (r>>3) & 63, rest = r >> 9;
    int t = rest >> 1, nt = rest & 1;
    int ic = (ln>>4)*8 + j, oc = nt*16 + (ln&15);
    wf[idx] = (_Float16)W32[(size_t)L*9216 + ((size_t)oc*32 + ic)*9 + t];
}

// ---------------- histogram of voxel ids (+ cache gids)
__global__ void kHist(const int* __restrict__ bid, const float* __restrict__ pts,
                      unsigned* __restrict__ offs, int* __restrict__ gids)
{
    int i = blockIdx.x*256 + threadIdx.x;
    if (i >= N_PTS) return;
    int gid = voxel_id(pts[i], pts[N_PTS+i], bid[i]);
    gids[i] = gid;
    atomicAdd(&offs[gid], 1u);
}

// ---------------- 3-kernel exclusive scan of offs[GRID_NUM]
__global__ void kScan1(unsigned* __restrict__ offs, unsigned* __restrict__ partials)
{
    __shared__ unsigned sa[256], sb[256];
    const int t = threadIdx.x;
    const int g = blockIdx.x*256 + t;
    unsigned v = offs[g];
    sa[t] = v;
    __syncthreads();
    unsigned* src = sa; unsigned* dst = sb;
    #pragma unroll
    for (int d=1; d<256; d<<=1){
        dst[t] = src[t] + ((t>=d) ? src[t-d] : 0u);
        __syncthreads();
        unsigned* tmp = src; src = dst; dst = tmp;
    }
    unsigned incl = src[t];
    offs[g] = incl - v;                    // exclusive within block
    if (t == 255) partials[blockIdx.x] = incl;
}
__global__ void kScan2(unsigned* __restrict__ partials)   // 4096 entries, 1 block
{
    __shared__ unsigned sa[256], sb[256];
    const int t = threadIdx.x;
    unsigned loc[16]; unsigned sum = 0;
    #pragma unroll
    for (int j=0;j<16;j++){ loc[j] = partials[t*16+j]; sum += loc[j]; }
    sa[t] = sum;
    __syncthreads();
    unsigned* src = sa; unsigned* dst = sb;
    #pragma unroll
    for (int d=1; d<256; d<<=1){
        dst[t] = src[t] + ((t>=d) ? src[t-d] : 0u);
        __syncthreads();
        unsigned* tmp = src; src = dst; dst = tmp;
    }
    unsigned run = src[t] - sum;           // exclusive base for this thread
    #pragma unroll
    for (int j=0;j<16;j++){ unsigned c = loc[j]; partials[t*16+j] = run; run += c; }
}
__global__ void kScan3(unsigned* __restrict__ offs, const unsigned* __restrict__ partials)
{
    int g = blockIdx.x*256 + threadIdx.x;
    offs[g] += partials[blockIdx.x];
}

// ---------------- Kernel A: MLPs -> obufA at SORTED position; record sGid + inv
__global__ void kA(const int* __restrict__ bid, const float* __restrict__ pts,
                   const int* __restrict__ gids,
                   const float* __restrict__ w0, const float* __restrict__ b0,
                   const float* __restrict__ s0, const float* __restrict__ t0,
                   const float* __restrict__ w1, const float* __restrict__ b1,
                   const float* __restrict__ s1, const float* __restrict__ t1,
                   const float* __restrict__ wv0, const float* __restrict__ bv0,
                   const float* __restrict__ sv0, const float* __restrict__ tv0,
                   u64* __restrict__ obufA, unsigned* __restrict__ offs,
                   int* __restrict__ sGid, unsigned* __restrict__ inv)
{
    int i = blockIdx.x*256 + threadIdx.x;
    if (i >= N_PTS) return;
    float p[6];
    #pragma unroll
    for (int r=0;r<6;r++) p[r] = pts[r*N_PTS+i];
    int xg = (int)floorf(p[0]*512.0f);
    int yg = (int)floorf(p[1]*512.0f);

    float h0[16];
    #pragma unroll
    for (int o=0;o<16;o++){
        float a = b0[o];
        #pragma unroll
        for (int k=0;k<6;k++) a = fmaf(w0[o*6+k], p[k], a);
        h0[o] = relu_(fmaf(a, s0[o], t0[o]));
    }
    float h1[16];
    #pragma unroll
    for (int o=0;o<16;o++){
        float a = b1[o];
        #pragma unroll
        for (int k=0;k<16;k++) a = fmaf(w1[o*16+k], h0[k], a);
        h1[o] = relu_(fmaf(a, s1[o], t1[o]));
    }
    float dx = p[0] - ((float)xg + 0.5f)*(1.0f/512.0f);
    float dy = p[1] - ((float)yg + 0.5f)*(1.0f/512.0f);
    float vv[16];
    #pragma unroll
    for (int o=0;o<16;o++){
        float a = bv0[o];
        #pragma unroll
        for (int k=0;k<16;k++) a = fmaf(wv0[o*18+k], h1[k], a);
        a = fmaf(wv0[o*18+16], dx, a);
        a = fmaf(wv0[o*18+17], dy, a);
        vv[o] = relu_(fmaf(a, sv0[o], tv0[o]));
    }
    int gid = gids[i];
    unsigned pos = atomicAdd(&offs[gid], 1u);
    u64* op = obufA + (size_t)pos*4;
    #pragma unroll
    for (int q=0;q<4;q++) op[q] = packh4(&vv[q*4]);
    sGid[pos] = gid;
    inv[i] = pos;
}

// ---------------- per-voxel max over its CONTIGUOUS segment: 16ch
__global__ void kSegMax(const unsigned* __restrict__ offs,
                        const u64* __restrict__ src, u64* __restrict__ dst)
{
    int v = blockIdx.x*256 + threadIdx.x;
    unsigned s = v ? offs[v-1] : 0u;
    unsigned e = offs[v];
    if (e <= s) return;
    u64 m0=0,m1=0,m2=0,m3=0;
    for (unsigned p=s; p<e; ++p){
        const u64* q = src + (size_t)p*4;
        m0 = pkmax4(m0, q[0]); m1 = pkmax4(m1, q[1]);
        m2 = pkmax4(m2, q[2]); m3 = pkmax4(m3, q[3]);
    }
    u64* d = dst + (size_t)v*4;
    d[0]=m0; d[1]=m1; d[2]=m2; d[3]=m3;
}

// ---------------- per-voxel max over contiguous segment, 32ch; write ALL voxels
__global__ void kGridMax(const unsigned* __restrict__ offs,
                         const u64* __restrict__ src, u64* __restrict__ dst)
{
    int v = blockIdx.x*256 + threadIdx.x;
    unsigned s = v ? offs[v-1] : 0u;
    unsigned e = offs[v];
    u64 m[8];
    #pragma unroll
    for (int q=0;q<8;q++) m[q] = 0ull;
    for (unsigned p=s; p<e; ++p){
        const u64* q = src + (size_t)p*8;
        #pragma unroll
        for (int j=0;j<8;j++) m[j] = pkmax4(m[j], q[j]);
    }
    u64* d = dst + (size_t)v*8;
    #pragma unroll
    for (int q=0;q<8;q++) d[q] = m[q];
}

// ---------------- Kernel B: sorted j: concat(obufA[j], seg0[sGid[j]]) -> obufB[j]
__global__ void kB(const int* __restrict__ sGid,
                   const float* __restrict__ w, const float* __restrict__ bb,
                   const float* __restrict__ ss, const float* __restrict__ tt,
                   const u64* __restrict__ obufA, const u64* __restrict__ seg0,
                   u64* __restrict__ obufB)
{
    int j = blockIdx.x*256 + threadIdx.x;
    if (j >= N_PTS) return;
    int gid = sGid[j];
    float h[32];
    const u64* ap = obufA + (size_t)j*4;
    #pragma unroll
    for (int q=0;q<4;q++) unpackh4(ap[q], &h[q*4]);
    const u64* sp = seg0 + (size_t)gid*4;
    #pragma unroll
    for (int q=0;q<4;q++) unpackh4(sp[q], &h[16+q*4]);

    float o[16];
    #pragma unroll
    for (int c=0;c<16;c++){
        float a = bb[c];
        #pragma unroll
        for (int k=0;k<32;k++) a = fmaf(w[c*32+k], h[k], a);
        o[c] = relu_(fmaf(a, ss[c], tt[c]));
    }
    u64* op = obufB + (size_t)j*4;
    #pragma unroll
    for (int q=0;q<4;q++) op[q] = packh4(&o[q*4]);
}

// ---------------- Kernel C: sorted j: concat(obufB[j], seg1[sGid[j]]) -> pconv(w2) -> pbuf[j]
__global__ void kC(const int* __restrict__ sGid,
                   const float* __restrict__ w, const float* __restrict__ bb,
                   const float* __restrict__ ss, const float* __restrict__ tt,
                   const u64* __restrict__ obufB, const u64* __restrict__ seg1,
                   u64* __restrict__ pbuf)
{
    int j = blockIdx.x*256 + threadIdx.x;
    if (j >= N_PTS) return;
    int gid = sGid[j];
    float h[32];
    const u64* ap = obufB + (size_t)j*4;
    #pragma unroll
    for (int q=0;q<4;q++) unpackh4(ap[q], &h[q*4]);
    const u64* sp = seg1 + (size_t)gid*4;
    #pragma unroll
    for (int q=0;q<4;q++) unpackh4(sp[q], &h[16+q*4]);

    float p0v[32];
    #pragma unroll
    for (int c=0;c<32;c++){
        float a = bb[c];
        #pragma unroll
        for (int k=0;k<32;k++) a = fmaf(w[c*32+k], h[k], a);
        p0v[c] = relu_(fmaf(a, ss[c], tt[c]));
    }
    u64* pp = pbuf + (size_t)j*8;
    #pragma unroll
    for (int q=0;q<8;q++) pp[q] = packh4(&p0v[q*4]);
}

// ---------------- dilated 3x3 conv + BN + ReLU via MFMA implicit GEMM
// + XCD-aware bijective tile swizzle (contiguous chunk of tiles per XCD)
template<int P>
__global__ __launch_bounds__(256,4) void convM(
    const _Float16* __restrict__ in, _Float16* __restrict__ out,
    const f16x8* __restrict__ wfrag, const float* __restrict__ bb,
    const float* __restrict__ ss, const float* __restrict__ tt)
{
    constexpr int TW = 32, TH = 8;
    constexpr int TIW = TW + 2*P, TIH = TH + 2*P;
    __shared__ uint4 sA[TIH*TIW*5];
    const int tid = threadIdx.x;
    const int lane = tid & 63, wv = tid >> 6;

    // XCD swizzle: nwg = 16*64*4 = 4096, divisible by 8. flat -> (flat&7)*512 + flat>>3
    int flat = blockIdx.x + 16*blockIdx.y + 1024*blockIdx.z;
    int swz  = (flat & 7)*512 + (flat >> 3);
    const int bx = swz & 15, by = (swz >> 4) & 63, bz = swz >> 10;
    const int x0 = bx*TW, y0 = by*TH;
    const _Float16* inB = in + (size_t)bz*VOX*32;

    for (int u = tid; u < TIH*TIW*4; u += 256){
        int g = u & 3;
        int pxr = u >> 2;
        int px = pxr % TIW, r = pxr / TIW;
        int gy = y0 - P + r, gx = x0 - P + px;
        uint4 v = make_uint4(0,0,0,0);
        if ((unsigned)gy < 512u && (unsigned)gx < 512u)
            v = *(const uint4*)(inB + (((size_t)gy*512 + gx)*32 + g*8));
        sA[(r*TIW + px)*5 + g] = v;
    }
    __syncthreads();

    const f16x8* pA = (const f16x8*)sA;
    const int aoff = (lane&15)*5 + (lane>>4);
    const int rowbase = wv*2;

    f32x4 acc[4][2];
    #pragma unroll
    for (int m=0;m<4;m++){ acc[m][0]=(f32x4)0.f; acc[m][1]=(f32x4)0.f; }

    #pragma unroll
    for (int t=0;t<9;t++){
        const int ky = t/3, kx = t%3;
        f16x8 b0 = wfrag[(t*2+0)*64 + lane];
        f16x8 b1 = wfrag[(t*2+1)*64 + lane];
        #pragma unroll
        for (int m=0;m<4;m++){
            int r = rowbase + (m>>1) + ky*P;
            int pxb = (m&1)*16 + kx*P;
            f16x8 a = pA[(r*TIW + pxb)*5 + aoff];
            acc[m][0] = __builtin_amdgcn_mfma_f32_16x16x32_f16(b0, a, acc[m][0], 0,0,0);
            acc[m][1] = __builtin_amdgcn_mfma_f32_16x16x32_f16(b1, a, acc[m][1], 0,0,0);
        }
    }

    float bn[2][4], sn[2][4], tn[2][4];
    #pragma unroll
    for (int n=0;n<2;n++){
        int ocb = n*16 + (lane>>4)*4;
        #pragma unroll
        for (int r=0;r<4;r++){ bn[n][r]=bb[ocb+r]; sn[n][r]=ss[ocb+r]; tn[n][r]=tt[ocb+r]; }
    }
    _Float16* outB = out + (size_t)bz*VOX*32;
    #pragma unroll
    for (int m=0;m<4;m++){
        int y  = y0 + rowbase + (m>>1);
        int px = x0 + (m&1)*16 + (lane&15);
        #pragma unroll
        for (int n=0;n<2;n++){
            unsigned h[4];
            #pragma unroll
            for (int r=0;r<4;r++){
                float v = relu_(fmaf(acc[m][n][r] + bn[n][r], sn[n][r], tn[n][r]));
                h[r] = (unsigned)__half_as_ushort(__float2half_rn(v));
            }
            uint2 val = make_uint2(h[0] | (h[1]<<16), h[2] | (h[3]<<16));
            *(uint2*)(outB + ((size_t)y*512 + px)*32 + n*16 + (lane>>4)*4) = val;
        }
    }
}

// ---------------- bilinear + head for ONE point (branch-free taps)
static __device__ __forceinline__ void final_accum_taps(
    const _Float16* __restrict__ gridH, float ix, float iy, float* p1)
{
    float x0f = floorf(ix), y0f = floorf(iy);
    float wx = ix - x0f, wy = iy - y0f;
    int x0 = (int)x0f, y0 = (int)y0f;
    #pragma unroll
    for (int t=0;t<4;t++){
        int yi = y0 + (t>>1);
        int xi = x0 + (t&1);
        bool ok = (yi >= 0) & (yi < BATCHN*YN) & (xi >= 0) & (xi < XN);
        float wgt = (((t>>1)? wy : 1.0f-wy) * ((t&1)? wx : 1.0f-wx)) * (ok ? 1.0f : 0.0f);
        int cy = min(max(yi,0), BATCHN*YN-1), cx = min(max(xi,0), XN-1);
        const uint4* tp = (const uint4*)(gridH + ((size_t)cy*XN + cx)*32);
        #pragma unroll
        for (int q=0;q<4;q++){
            uint4 v = tp[q];
            const unsigned int* vu = (const unsigned int*)&v;
            #pragma unroll
            for (int e=0;e<4;e++){
                float lo = __half2float(__ushort_as_half((unsigned short)(vu[e] & 0xFFFF)));
                float hi = __half2float(__ushort_as_half((unsigned short)(vu[e] >> 16)));
                p1[q*8 + e*2 + 0] = fmaf(wgt, lo, p1[q*8 + e*2 + 0]);
                p1[q*8 + e*2 + 1] = fmaf(wgt, hi, p1[q*8 + e*2 + 1]);
            }
        }
    }
}

// ---------------- kFinal: 2 points/thread (i, i+N_HALF), branch-free, batched loads
__global__ __launch_bounds__(256) void kFinal(
    const int* __restrict__ bid, const float* __restrict__ pts,
    const unsigned* __restrict__ inv, const u64* __restrict__ pbuf,
    const _Float16* __restrict__ gridH,
    const float* __restrict__ w3, const float* __restrict__ b3,
    float* __restrict__ outp)
{
    int t = blockIdx.x*256 + threadIdx.x;
    if (t >= N_HALF) return;
    int ia = t, ib = t + N_HALF;

    float pxa = pts[ia], pya = pts[N_PTS+ia];
    float pxb = pts[ib], pyb = pts[N_PTS+ib];
    int ba = bid[ia], bbatch = bid[ib];
    unsigned ja = inv[ia], jb = inv[ib];

    // point0 packed loads (issue early)
    u64 pka[8], pkb[8];
    const u64* ppa = pbuf + (size_t)ja*8;
    const u64* ppb = pbuf + (size_t)jb*8;
    #pragma unroll
    for (int q=0;q<8;q++){ pka[q] = ppa[q]; pkb[q] = ppb[q]; }

    float p1a[32], p1b[32];
    #pragma unroll
    for (int c=0;c<32;c++){ p1a[c]=0.f; p1b[c]=0.f; }

    final_accum_taps(gridH, pxa*512.0f - 1.0f, pya*512.0f - 1.0f + (float)(ba*512), p1a);
    final_accum_taps(gridH, pxb*512.0f - 1.0f, pyb*512.0f - 1.0f + (float)(bbatch*512), p1b);

    float p0a[32], p0b[32];
    #pragma unroll
    for (int q=0;q<8;q++){ unpackh4(pka[q], &p0a[q*4]); unpackh4(pkb[q], &p0b[q*4]); }

    #pragma unroll
    for (int k=0;k<20;k++){
        float aa = b3[k], ab = b3[k];
        #pragma unroll
        for (int c=0;c<32;c++){
            float wlo = w3[k*64+c], whi = w3[k*64+32+c];
            aa = fmaf(wlo, p0a[c], aa); aa = fmaf(whi, p1a[c], aa);
            ab = fmaf(wlo, p0b[c], ab); ab = fmaf(whi, p1b[c], ab);
        }
        outp[(size_t)k*N_PTS + ia] = aa;
        outp[(size_t)k*N_PTS + ib] = ab;
    }
}

extern "C" void kernel_launch(void* const* d_in, const int* in_sizes, int n_in,
                              void* d_out, int out_size, void* d_ws, size_t ws_size,
                              hipStream_t stream)
{
    const int*   bid = (const int*)  d_in[0];
    const float* pts = (const float*)d_in[1];
    const float* w0  = (const float*)d_in[3];
    const float* b0  = (const float*)d_in[4];
    const float* s0  = (const float*)d_in[5];
    const float* t0  = (const float*)d_in[6];
    const float* w1  = (const float*)d_in[7];
    const float* b1  = (const float*)d_in[8];
    const float* s1  = (const float*)d_in[9];
    const float* t1  = (const float*)d_in[10];
    const float* wv0 = (const float*)d_in[11];
    const float* bv0 = (const float*)d_in[12];
    const float* sv0 = (const float*)d_in[13];
    const float* tv0 = (const float*)d_in[14];
    const float* wv1 = (const float*)d_in[15];
    const float* bv1 = (const float*)d_in[16];
    const float* sv1 = (const float*)d_in[17];
    const float* tv1 = (const float*)d_in[18];
    const float* w2  = (const float*)d_in[19];
    const float* b2  = (const float*)d_in[20];
    const float* s2  = (const float*)d_in[21];
    const float* t2  = (const float*)d_in[22];
    const float* w2d = (const float*)d_in[23];
    const float* b2d = (const float*)d_in[24];
    const float* s2d = (const float*)d_in[25];
    const float* t2d = (const float*)d_in[26];
    const float* w3  = (const float*)d_in[27];
    const float* b3  = (const float*)d_in[28];

    const size_t MB = 1024*1024;
    const size_t NEED = 192*MB;
    if (ws_size < NEED){
        kDiag<<<512,256,0,stream>>>((float*)d_out, out_size, (float)(ws_size>>20));
        return;
    }

    char* ws = (char*)d_ws;
    u64*      gridV    = (u64*)ws;                        // 64 MiB NHWC fp16 (conv ping)
    _Float16* ping     = (_Float16*)ws;
    _Float16* pong     = (_Float16*)(ws + 64*MB);         // 64 MiB (conv pong)
    u64*      seg0     = (u64*)(ws + 64*MB);              // 32 MiB, alias pong (dead before conv0)
    u64*      seg1     = (u64*)(ws + 96*MB);              // 32 MiB, alias pong
    unsigned* offs     = (unsigned*)(ws + 128*MB);        // 4 MiB hist/offsets
    unsigned* partials = (unsigned*)(ws + 132*MB);        // 16 KiB
    int*      sGid     = (int*)(ws + 133*MB);             // 1.6 MiB (sorted gid)
    int*      gids     = (int*)(ws + 135*MB);             // 1.6 MiB (original order)
    unsigned* inv      = (unsigned*)(ws + 137*MB);        // 1.6 MiB (orig -> sorted pos)
    u64*      obufA    = (u64*)(ws + 139*MB);             // 12.8 MiB sorted [pos][16ch]
    u64*      obufB    = (u64*)(ws + 152*MB);             // 12.8 MiB
    u64*      pbuf     = (u64*)(ws + 165*MB);             // 25.6 MiB sorted [pos][32ch]
    _Float16* wfrag    = (_Float16*)(ws + 191*MB);        // 72 KiB prepped weights

    // zero the histogram only
    kZero<<<256,256,0,stream>>>((float4*)offs, (int)(GRID_NUM*4/16));
    kWprep<<<144,256,0,stream>>>(w2d, wfrag);

    const int nb = (N_PTS + 255)/256;
    const int nv = GRID_NUM/256;                          // 4096

    kHist <<<nb,256,0,stream>>>(bid, pts, offs, gids);
    kScan1<<<nv,256,0,stream>>>(offs, partials);
    kScan2<<<1,256,0,stream>>>(partials);
    kScan3<<<nv,256,0,stream>>>(offs, partials);

    kA<<<nb,256,0,stream>>>(bid, pts, gids, w0,b0,s0,t0, w1,b1,s1,t1,
                            wv0,bv0,sv0,tv0, obufA, offs, sGid, inv);
    kSegMax<<<nv,256,0,stream>>>(offs, obufA, seg0);
    kB<<<nb,256,0,stream>>>(sGid, wv1,bv1,sv1,tv1, obufA, seg0, obufB);
    kSegMax<<<nv,256,0,stream>>>(offs, obufB, seg1);
    kC<<<nb,256,0,stream>>>(sGid, w2,b2,s2,t2, obufB, seg1, pbuf);
    kGridMax<<<nv,256,0,stream>>>(offs, pbuf, gridV);

    dim3 cgrid(XN/32, YN/8, BATCHN);
    const f16x8* wf = (const f16x8*)wfrag;
    convM<1><<<cgrid,256,0,stream>>>(ping, pong, wf + 0*1152, b2d + 0,  s2d + 0,  t2d + 0);
    convM<2><<<cgrid,256,0,stream>>>(pong, ping, wf + 1*1152, b2d + 32, s2d + 32, t2d + 32);
    convM<2><<<cgrid,256,0,stream>>>(ping, pong, wf + 2*1152, b2d + 64, s2d + 64, t2d + 64);
    convM<2><<<cgrid,256,0,stream>>>(pong, ping, wf + 3*1152, b2d + 96, s2d + 96, t2d + 96);

    const int nbh = (N_HALF + 255)/256;
    kFinal<<<nbh,256,0,stream>>>(bid, pts, inv, pbuf, ping, w3, b3, (float*)d_out);
}